// Round 1
// baseline (209.323 us; speedup 1.0000x reference)
//
#include <hip/hip_runtime.h>

// MomentumSSM B=2, L=4096, D=512, N=16, R=32, P=64 — chunk-parallel scan, NCH=256.
// R15: 6 dispatches
//   k_wprep -> k_proj (MFMA bf16x3) -> k_dt (MFMA, K=32) -> k_scan1 -> k_fix -> k_scan2
// - dt_lin = proj[:, :32] @ W_dt^T extracted to MFMA kernel k_dt (softplus -> f16 dth)
//   => scan1 loses its scalar dt loop (~40% of VALU, ~2/3 of LDS reads)
// - both scans pinned to 4 waves/SIMD via __launch_bounds__(256,4) (scan2 was VGPR=132 -> 3)
// - Ps staging shrunk to the proj columns actually read (scan1: B cols, scan2: B+C cols)
// - fp16 inter-kernel state (hh/vh/cv/dt), fp32 arithmetic
// - a_n = exp2(dt*A2[n]) as running product r^(n+1) when A2 is an arithmetic
//   progression (runtime-verified; general-exp fallback)
// Disproven paths: coop launch (fails), manual grid barrier (~80us/sync), dynamic-index
// prefetch arrays (scratch spill), dt recompute in scan2 (neutral-negative).
//
// v_t = beta*v + alpha*inp ; h_t = a_t*h + v ; a_t = exp(dt*A_n)
// chunk map: h_end = Pa*H0 + cv*V0 + hhat ; v_end = beta^LCH*V0 + vhat

#define D_IN 512
#define D_ST 16
#define DTR  32
#define BSZ  2
#define LSEQ 4096
#define PDIM 64
#define NCH  256
#define LCH  (LSEQ / NCH)  // 16
#define LOG2E 1.44269504f
#define LN2   0.69314718f

typedef __attribute__((ext_vector_type(8))) short short8;
typedef __attribute__((ext_vector_type(4))) float f32x4;
typedef _Float16 f16;
typedef __attribute__((ext_vector_type(8))) _Float16 f16x8;

// W_dt bf16 hi/lo split lives in device globals (no workspace growth)
__device__ __align__(16) short g_Wdh[D_IN * DTR];
__device__ __align__(16) short g_Wdl[D_IN * DTR];

__device__ inline float fast_exp2(float x) { return __builtin_amdgcn_exp2f(x); }
__device__ inline float fast_log2(float x) { return __builtin_amdgcn_logf(x); }

__device__ inline unsigned short bf16_rne(float f) {
  unsigned b = __float_as_uint(f);
  return (unsigned short)((b + 0x7fffu + ((b >> 16) & 1u)) >> 16);
}

__device__ inline void cvt8(const float4 u, const float4 v, short8& hi, short8& lo) {
  float f[8] = {u.x, u.y, u.z, u.w, v.x, v.y, v.z, v.w};
#pragma unroll
  for (int i = 0; i < 8; ++i) {
    unsigned short h = bf16_rne(f[i]);
    hi[i] = (short)h;
    float r = f[i] - __uint_as_float((unsigned)h << 16);
    lo[i] = (short)bf16_rne(r);
  }
}

__device__ inline void st16h(f16* p, const float* s) {
  f16 t[16];
#pragma unroll
  for (int i = 0; i < 16; ++i) t[i] = (f16)s[i];
  *(f16x8*)p = *(f16x8*)&t[0];
  *(f16x8*)(p + 8) = *(f16x8*)&t[8];
}
__device__ inline void ld16h(const f16* p, float* d) {
  f16x8 a = *(const f16x8*)p;
  f16x8 b = *(const f16x8*)(p + 8);
#pragma unroll
  for (int i = 0; i < 8; ++i) { d[i] = (float)a[i]; d[8 + i] = (float)b[i]; }
}

// load A2 row; detect arithmetic-progression structure (A2[n]=(n+1)*A2[0])
__device__ inline bool loadA2(const float* A_log, int d, float* A2) {
  const float4* ap = (const float4*)(A_log + (size_t)d * D_ST);
#pragma unroll
  for (int i = 0; i < 4; ++i) {
    float4 a4 = ap[i];
    A2[4 * i + 0] = -__expf(a4.x) * LOG2E;
    A2[4 * i + 1] = -__expf(a4.y) * LOG2E;
    A2[4 * i + 2] = -__expf(a4.z) * LOG2E;
    A2[4 * i + 3] = -__expf(a4.w) * LOG2E;
  }
  bool pw = true;
#pragma unroll
  for (int n = 1; n < 16; ++n) {
    float ref = (float)(n + 1) * A2[0];
    pw = pw && (fabsf(A2[n] - ref) <= 2e-5f * fabsf(ref));
  }
  return pw;
}

// ---------------- W_xproj + W_dt -> bf16 hi/lo split -------------------------
__global__ __launch_bounds__(256) void k_wprep(const float* __restrict__ W,
                                               const float* __restrict__ Wdt,
                                               short* __restrict__ Whi,
                                               short* __restrict__ Wlo) {
  const int i = (blockIdx.x * 256 + threadIdx.x) * 4;
  const float* src;
  short *dh, *dl;
  if (i < PDIM * D_IN) {
    src = W + i; dh = Whi + i; dl = Wlo + i;
  } else {
    const int k = i - PDIM * D_IN;
    src = Wdt + k; dh = g_Wdh + k; dl = g_Wdl + k;
  }
  float4 w = *(const float4*)src;
  float f[4] = {w.x, w.y, w.z, w.w};
  unsigned short h[4], lo[4];
#pragma unroll
  for (int j = 0; j < 4; ++j) {
    h[j] = bf16_rne(f[j]);
    float r = f[j] - __uint_as_float((unsigned)h[j] << 16);
    lo[j] = bf16_rne(r);
  }
  *(uint2*)dh = make_uint2(h[0] | ((unsigned)h[1] << 16), h[2] | ((unsigned)h[3] << 16));
  *(uint2*)dl = make_uint2(lo[0] | ((unsigned)lo[1] << 16), lo[2] | ((unsigned)lo[3] << 16));
}

// ---------------- proj = x @ W^T via MFMA bf16x3 (R5-proven) -----------------
#define MM3(ACC, AH, AL, BH, BL)                                        \
  ACC = __builtin_amdgcn_mfma_f32_16x16x32_bf16(AL, BH, ACC, 0, 0, 0);  \
  ACC = __builtin_amdgcn_mfma_f32_16x16x32_bf16(AH, BL, ACC, 0, 0, 0);  \
  ACC = __builtin_amdgcn_mfma_f32_16x16x32_bf16(AH, BH, ACC, 0, 0, 0);

#define LOADB(P, S)                                   \
  {                                                   \
    const int kb = ((S) & 15) * 32;                   \
    P##h0 = *(const short8*)(bh + kb);                \
    P##h1 = *(const short8*)(bh + 8192 + kb);         \
    P##h2 = *(const short8*)(bh + 16384 + kb);        \
    P##h3 = *(const short8*)(bh + 24576 + kb);        \
    P##l0 = *(const short8*)(bl + kb);                \
    P##l1 = *(const short8*)(bl + 8192 + kb);         \
    P##l2 = *(const short8*)(bl + 16384 + kb);        \
    P##l3 = *(const short8*)(bl + 24576 + kb);        \
  }

#define LOADA(Aa, Ab, S)                              \
  {                                                   \
    const int ka = ((S) & 15) * 32;                   \
    Aa = *(const float4*)(xr + ka);                   \
    Ab = *(const float4*)(xr + ka + 4);               \
  }

#define SUBSTEP(Aa, Ab, P, SA, SB)                    \
  {                                                   \
    short8 ahi, alo;                                  \
    cvt8(Aa, Ab, ahi, alo);                           \
    MM3(acc0, ahi, alo, P##h0, P##l0);                \
    MM3(acc1, ahi, alo, P##h1, P##l1);                \
    MM3(acc2, ahi, alo, P##h2, P##l2);                \
    MM3(acc3, ahi, alo, P##h3, P##l3);                \
    LOADB(P, SB);                                     \
    LOADA(Aa, Ab, SA);                                \
  }

__global__ __launch_bounds__(64) void k_proj(const float* __restrict__ x,
                                             const short* __restrict__ Whi,
                                             const short* __restrict__ Wlo,
                                             float* __restrict__ proj) {
  const int row0 = blockIdx.x * 16;
  const int l = threadIdx.x;
  const int m = l & 15;
  const int ko = (l >> 4) * 8;
  const float* xr = x + (size_t)(row0 + m) * D_IN + ko;
  const short* bh = Whi + (size_t)m * D_IN + ko;
  const short* bl = Wlo + (size_t)m * D_IN + ko;

  f32x4 acc0 = {0.f, 0.f, 0.f, 0.f}, acc1 = acc0, acc2 = acc0, acc3 = acc0;
  float4 A0a, A0b, A1a, A1b, A2a, A2b, A3a, A3b;
  short8 Xh0, Xh1, Xh2, Xh3, Xl0, Xl1, Xl2, Xl3;
  short8 Yh0, Yh1, Yh2, Yh3, Yl0, Yl1, Yl2, Yl3;
  LOADA(A0a, A0b, 0); LOADA(A1a, A1b, 1); LOADA(A2a, A2b, 2); LOADA(A3a, A3b, 3);
  LOADB(X, 0); LOADB(Y, 1);

#pragma unroll
  for (int it = 0; it < 4; ++it) {
    const int s = it * 4;
    SUBSTEP(A0a, A0b, X, s + 4, s + 2);
    SUBSTEP(A1a, A1b, Y, s + 5, s + 3);
    SUBSTEP(A2a, A2b, X, s + 6, s + 4);
    SUBSTEP(A3a, A3b, Y, s + 7, s + 5);
  }

  const int r0 = (l >> 4) * 4;
#pragma unroll
  for (int r = 0; r < 4; ++r) {
    float* pr = proj + (size_t)(row0 + r0 + r) * PDIM + m;
    pr[0] = acc0[r]; pr[16] = acc1[r]; pr[32] = acc2[r]; pr[48] = acc3[r];
  }
}

// ---------------- dt = softplus(proj[:, :32] @ W_dt^T + b_dt) via MFMA -------
// K=32 == one 16x16x32 step; mirrors k_proj's harness-proven fragment layout.
__global__ __launch_bounds__(64) void k_dt(const float* __restrict__ proj,
                                           const float* __restrict__ b_dt,
                                           f16* __restrict__ dth) {
  const int row0 = blockIdx.x * 16;   // t over B*L
  const int col0 = blockIdx.y * 64;   // d
  const int l = threadIdx.x;
  const int m = l & 15;
  const int ko = (l >> 4) * 8;        // k in {0,8,16,24} -> K=32 covered
  const float* ap = proj + (size_t)(row0 + m) * PDIM + ko;
  const short* bh = g_Wdh + (col0 + m) * DTR + ko;
  const short* bl = g_Wdl + (col0 + m) * DTR + ko;

  float4 Aa = *(const float4*)ap;
  float4 Ab = *(const float4*)(ap + 4);
  short8 ahi, alo;
  cvt8(Aa, Ab, ahi, alo);
  short8 B0h = *(const short8*)bh;
  short8 B1h = *(const short8*)(bh + 16 * DTR);
  short8 B2h = *(const short8*)(bh + 32 * DTR);
  short8 B3h = *(const short8*)(bh + 48 * DTR);
  short8 B0l = *(const short8*)bl;
  short8 B1l = *(const short8*)(bl + 16 * DTR);
  short8 B2l = *(const short8*)(bl + 32 * DTR);
  short8 B3l = *(const short8*)(bl + 48 * DTR);

  f32x4 acc0 = {0.f, 0.f, 0.f, 0.f}, acc1 = acc0, acc2 = acc0, acc3 = acc0;
  MM3(acc0, ahi, alo, B0h, B0l);
  MM3(acc1, ahi, alo, B1h, B1l);
  MM3(acc2, ahi, alo, B2h, B2l);
  MM3(acc3, ahi, alo, B3h, B3l);

  float bb[4];
#pragma unroll
  for (int cc = 0; cc < 4; ++cc) bb[cc] = b_dt[col0 + m + 16 * cc];

  const int r0 = (l >> 4) * 4;
#pragma unroll
  for (int r = 0; r < 4; ++r) {
    const size_t t = (size_t)(row0 + r0 + r);
    float vals[4] = {acc0[r], acc1[r], acc2[r], acc3[r]};
#pragma unroll
    for (int cc = 0; cc < 4; ++cc) {
      float a = vals[cc] + bb[cc];
      float e = fast_exp2(a * LOG2E);
      float dt = (a > 20.f) ? a : LN2 * fast_log2(1.f + e);
      dth[t * D_IN + col0 + m + 16 * cc] = (f16)dt;
    }
  }
}

// ---------------- pass 1: read dt(f16), zero-init scan, fp16 state out -------
#define S1_BODY(GET_A)                                        \
  _Pragma("unroll")                                           \
  for (int j = 0; j < LCH; ++j) {                             \
    const float dtc = dtv[j], xv = xs[j];                     \
    sd += dtc;                                                \
    bpow *= beta;                                             \
    const float u = alpha * dtc * xv;                         \
    GET_A;                                                    \
    float4 Bq[4];                                             \
    _Pragma("unroll")                                         \
    for (int i = 0; i < 4; ++i) Bq[i] = ((const float4*)&Ps[j][0])[i]; \
    const float* Bf = (const float*)Bq;                       \
    float ar = 1.f;                                           \
    _Pragma("unroll")                                         \
    for (int n = 0; n < 16; ++n) {                            \
      NEXT_A(ar, n);                                          \
      v[n] = fmaf(beta, v[n], u * Bf[n]);                     \
      h[n] = fmaf(ar, h[n], v[n]);                            \
      cv[n] = fmaf(ar, cv[n], bpow);                          \
    }                                                         \
  }

__global__ __launch_bounds__(256, 4) void k_scan1(const float* __restrict__ x,
                                                  const f16* __restrict__ dth,
                                                  const float* __restrict__ proj,
                                                  const float* __restrict__ A_log,
                                                  const float* __restrict__ alpha_p,
                                                  const float* __restrict__ beta_p,
                                                  f16* __restrict__ hh,
                                                  f16* __restrict__ vh,
                                                  f16* __restrict__ cvv,
                                                  float* __restrict__ sdt) {
  __shared__ float Ps[LCH][D_ST];  // proj cols 32..47 (B) only, 1 KB
  const int c = blockIdx.x, b = blockIdx.z;
  const int d = blockIdx.y * 256 + threadIdx.x;
  const int t0 = c * LCH;
  if (threadIdx.x < 64) {
    const float4* src = (const float4*)(proj + ((size_t)b * LSEQ + t0) * PDIM);
    ((float4*)&Ps[0][0])[threadIdx.x] =
        src[(threadIdx.x >> 2) * (PDIM / 4) + (DTR / 4) + (threadIdx.x & 3)];
  }
  float xs[LCH], dtv[LCH];
  {
    const float* xp = x + ((size_t)b * LSEQ + t0) * D_IN + d;
    const f16* dp = dth + ((size_t)b * LSEQ + t0) * D_IN + d;
#pragma unroll
    for (int j = 0; j < LCH; ++j) xs[j] = xp[(size_t)j * D_IN];
#pragma unroll
    for (int j = 0; j < LCH; ++j) dtv[j] = (float)dp[(size_t)j * D_IN];
  }
  const float alpha = alpha_p[0];
  const float beta = 1.f / (1.f + __expf(-beta_p[0]));
  float A2[D_ST];
  const bool powA = loadA2(A_log, d, A2);
  __syncthreads();

  float h[16] = {}, v[16] = {}, cv[16] = {};
  float bpow = 1.f, sd = 0.f;
  if (powA) {
#define NEXT_A(ar, n) ar *= r
    S1_BODY(const float r = fast_exp2(dtc * A2[0]))
#undef NEXT_A
  } else {
#define NEXT_A(ar, n) ar = fast_exp2(dtc * A2[n])
    S1_BODY()
#undef NEXT_A
  }

  const size_t base = ((size_t)(b * NCH + c) * D_IN + d) * D_ST;
  st16h(hh + base, h);
  st16h(vh + base, v);
  st16h(cvv + base, cv);
  sdt[(size_t)(b * NCH + c) * D_IN + d] = sd;
}

// ---------------- fixup: scan over 256 chunks; group-8 lookahead -------------
__global__ __launch_bounds__(64) void k_fix(f16* __restrict__ hh,
                                            f16* __restrict__ vh,
                                            const f16* __restrict__ cvv,
                                            const float* __restrict__ sdt,
                                            const float* __restrict__ A_log,
                                            const float* __restrict__ beta_p) {
  const int g = blockIdx.x * 64 + threadIdx.x;  // 16384 = B * D * N
  const int b = g >> 13;
  const int dn = g & 8191;
  const float beta = 1.f / (1.f + __expf(-beta_p[0]));
  const float A2 = -__expf(A_log[dn]) * LOG2E;
  float bL = beta;
#pragma unroll
  for (int i = 0; i < 4; ++i) bL *= bL;  // beta^16 = beta^LCH

  const size_t cs = (size_t)D_IN * D_ST;
  const size_t base = (size_t)b * NCH * cs + dn;
  const size_t sbase = (size_t)b * NCH * D_IN + (dn >> 4);

  float hg[8], vg[8], cg[8], sg[8];
#pragma unroll
  for (int i = 0; i < 8; ++i) {
    hg[i] = (float)hh[base + i * cs];
    vg[i] = (float)vh[base + i * cs];
    cg[i] = (float)cvv[base + i * cs];
    sg[i] = sdt[sbase + i * D_IN];
  }
  float H = 0.f, V = 0.f;
  for (int c0 = 0; c0 < NCH; c0 += 8) {
    const int cp = (c0 + 8) & (NCH - 1);  // wraps; last prefetch unused
    float hn[8], vn[8], cn[8], sn[8];
#pragma unroll
    for (int i = 0; i < 8; ++i) {
      hn[i] = (float)hh[base + (size_t)(cp + i) * cs];
      vn[i] = (float)vh[base + (size_t)(cp + i) * cs];
      cn[i] = (float)cvv[base + (size_t)(cp + i) * cs];
      sn[i] = sdt[sbase + (size_t)(cp + i) * D_IN];
    }
#pragma unroll
    for (int i = 0; i < 8; ++i) {
      hh[base + (size_t)(c0 + i) * cs] = (f16)H;
      vh[base + (size_t)(c0 + i) * cs] = (f16)V;
      const float Pa = fast_exp2(sg[i] * A2);
      const float Hn = fmaf(Pa, H, fmaf(cg[i], V, hg[i]));
      V = fmaf(bL, V, vg[i]);
      H = Hn;
    }
#pragma unroll
    for (int i = 0; i < 8; ++i) { hg[i] = hn[i]; vg[i] = vn[i]; cg[i] = cn[i]; sg[i] = sn[i]; }
  }
}

// ---------------- pass 2: read dt(fp16)+x, correct-init scan, emit y ---------
#define S2_BODY(GET_A)                                        \
  _Pragma("unroll")                                           \
  for (int j = 0; j < LCH; ++j) {                             \
    const float dtc = dtv[j], xv = xs[j];                     \
    const float u = alpha * dtc * xv;                         \
    GET_A;                                                    \
    float4 Bq[8];                                             \
    _Pragma("unroll")                                         \
    for (int i = 0; i < 8; ++i) Bq[i] = ((const float4*)&Ps[j][0])[i]; \
    const float* Bf = (const float*)Bq;                       \
    float y0 = 0.f, y1 = 0.f, y2 = 0.f, y3 = 0.f;             \
    float ar = 1.f;                                           \
    _Pragma("unroll")                                         \
    for (int n = 0; n < 16; ++n) {                            \
      NEXT_A(ar, n);                                          \
      v[n] = fmaf(beta, v[n], u * Bf[n]);                     \
      h[n] = fmaf(ar, h[n], v[n]);                            \
      float hc = h[n] * Bf[16 + n];                           \
      if ((n & 3) == 0) y0 += hc;                             \
      else if ((n & 3) == 1) y1 += hc;                        \
      else if ((n & 3) == 2) y2 += hc;                        \
      else y3 += hc;                                          \
    }                                                         \
    op[(size_t)j * D_IN] = (y0 + y1) + (y2 + y3) + Dv * xv;   \
  }

__global__ __launch_bounds__(256, 4) void k_scan2(const float* __restrict__ x,
                                                  const f16* __restrict__ dth,
                                                  const float* __restrict__ proj,
                                                  const float* __restrict__ A_log,
                                                  const float* __restrict__ D_param,
                                                  const float* __restrict__ alpha_p,
                                                  const float* __restrict__ beta_p,
                                                  const f16* __restrict__ hh,
                                                  const f16* __restrict__ vh,
                                                  float* __restrict__ out) {
  __shared__ float Ps[LCH][2 * D_ST];  // proj cols 32..63 (B,C), 2 KB
  const int c = blockIdx.x, b = blockIdx.z;
  const int d = blockIdx.y * 256 + threadIdx.x;
  const int t0 = c * LCH;
  if (threadIdx.x < 128) {
    const float4* src = (const float4*)(proj + ((size_t)b * LSEQ + t0) * PDIM);
    ((float4*)&Ps[0][0])[threadIdx.x] =
        src[(threadIdx.x >> 3) * (PDIM / 4) + (DTR / 4) + (threadIdx.x & 7)];
  }
  float xs[LCH], dtv[LCH];
  {
    const float* xp = x + ((size_t)b * LSEQ + t0) * D_IN + d;
    const f16* dp = dth + ((size_t)b * LSEQ + t0) * D_IN + d;
#pragma unroll
    for (int j = 0; j < LCH; ++j) xs[j] = xp[(size_t)j * D_IN];
#pragma unroll
    for (int j = 0; j < LCH; ++j) dtv[j] = (float)dp[(size_t)j * D_IN];
  }
  const float alpha = alpha_p[0];
  const float beta = 1.f / (1.f + __expf(-beta_p[0]));
  const float Dv = D_param[d];
  float A2[D_ST];
  const bool powA = loadA2(A_log, d, A2);
  const size_t ibase = ((size_t)(b * NCH + c) * D_IN + d) * D_ST;
  float h[16], v[16];
  ld16h(hh + ibase, h);
  ld16h(vh + ibase, v);
  __syncthreads();

  float* op = out + ((size_t)b * LSEQ + t0) * D_IN + d;
  if (powA) {
#define NEXT_A(ar, n) ar *= r
    S2_BODY(const float r = fast_exp2(dtc * A2[0]))
#undef NEXT_A
  } else {
#define NEXT_A(ar, n) ar = fast_exp2(dtc * A2[n])
    S2_BODY()
#undef NEXT_A
  }
}

extern "C" void kernel_launch(void* const* d_in, const int* in_sizes, int n_in,
                              void* d_out, int out_size, void* d_ws, size_t ws_size,
                              hipStream_t stream) {
  const float* x = (const float*)d_in[0];
  const float* A_log = (const float*)d_in[1];
  const float* D_param = (const float*)d_in[2];
  const float* W_xproj = (const float*)d_in[3];
  const float* W_dt = (const float*)d_in[4];
  const float* b_dt = (const float*)d_in[5];
  const float* alpha = (const float*)d_in[6];
  const float* beta_logit = (const float*)d_in[7];
  float* out = (float*)d_out;

  const size_t NST = (size_t)BSZ * NCH * D_IN * D_ST;  // 4194304
  float* ws = (float*)d_ws;
  float* proj = ws;                                  // 524288 floats
  float* sdt = proj + (size_t)BSZ * LSEQ * PDIM;     // 262144 floats
  f16* hh = (f16*)(sdt + (size_t)BSZ * NCH * D_IN);  // 4194304 halves
  f16* vh = hh + NST;
  f16* cvv = vh + NST;
  f16* dth = cvv + NST;                              // B*L*D halves
  short* Whi = (short*)(dth + (size_t)BSZ * LSEQ * D_IN);
  short* Wlo = Whi + (size_t)PDIM * D_IN;            // total ~37 MB

  k_wprep<<<dim3((PDIM * D_IN + D_IN * DTR) / 1024), dim3(256), 0, stream>>>(
      W_xproj, W_dt, Whi, Wlo);
  k_proj<<<dim3(BSZ * LSEQ / 16), dim3(64), 0, stream>>>(x, Whi, Wlo, proj);
  k_dt<<<dim3(BSZ * LSEQ / 16, D_IN / 64), dim3(64), 0, stream>>>(proj, b_dt, dth);
  k_scan1<<<dim3(NCH, D_IN / 256, BSZ), dim3(256), 0, stream>>>(
      x, dth, proj, A_log, alpha, beta_logit, hh, vh, cvv, sdt);
  k_fix<<<dim3(BSZ * D_IN * D_ST / 64), dim3(64), 0, stream>>>(hh, vh, cvv, sdt, A_log,
                                                               beta_logit);
  k_scan2<<<dim3(NCH, D_IN / 256, BSZ), dim3(256), 0, stream>>>(
      x, dth, proj, A_log, D_param, alpha, beta_logit, hh, vh, out);
}

// Round 2
// 208.448 us; speedup vs baseline: 1.0042x; 1.0042x over previous
//
#include <hip/hip_runtime.h>

// MomentumSSM B=2, L=4096, D=512, N=16, R=32, P=64 — chunk-parallel scan, NCH=256.
// R16: R12 structure (5 dispatches, proven 172 us) + scan1 lane-pair state split.
//   k_wprep -> k_proj (MFMA bf16x3) -> k_scan1 -> k_fix -> k_scan2
// - scan1: each d-channel handled by a LANE PAIR (tid&1 = state half, 8 states each).
//   2x waves (grid.y 2->4), ~2/3 per-thread regs -> hides the 78% stall seen at
//   VALUBusy=22%/occ=18%. dt GEMM computed redundantly by both halves (VALU is idle;
//   R15 proved materializing dt through HBM between kernels is a net loss).
// - hh/vh/cvv/sdt/dth layouts BIT-IDENTICAL to R12 -> k_fix/k_scan2 untouched.
// - fp16 inter-kernel state (hh/vh/cv/dt), fp32 arithmetic
// - a_n = exp2(dt*A2[n]) as running product (arith-progression fast path, runtime-
//   verified; general-exp fallback). Half 1 seeds ar = r^8 via 3 squarings.
// Disproven: coop launch (fails), manual grid barrier (~80us/sync), dynamic-index
// prefetch arrays (scratch spill), dt recompute in scan2 (neutral-negative),
// dt extraction to separate MFMA kernel (R15: +37us, cross-XCD dth traffic).
//
// v_t = beta*v + alpha*inp ; h_t = a_t*h + v ; a_t = exp(dt*A_n)
// chunk map: h_end = Pa*H0 + cv*V0 + hhat ; v_end = beta^LCH*V0 + vhat

#define D_IN 512
#define D_ST 16
#define DTR  32
#define BSZ  2
#define LSEQ 4096
#define PDIM 64
#define NCH  256
#define LCH  (LSEQ / NCH)  // 16
#define LOG2E 1.44269504f
#define LN2   0.69314718f

typedef __attribute__((ext_vector_type(8))) short short8;
typedef __attribute__((ext_vector_type(4))) float f32x4;
typedef _Float16 f16;
typedef __attribute__((ext_vector_type(8))) _Float16 f16x8;

__device__ inline float fast_exp2(float x) { return __builtin_amdgcn_exp2f(x); }
__device__ inline float fast_log2(float x) { return __builtin_amdgcn_logf(x); }

__device__ inline unsigned short bf16_rne(float f) {
  unsigned b = __float_as_uint(f);
  return (unsigned short)((b + 0x7fffu + ((b >> 16) & 1u)) >> 16);
}

__device__ inline void cvt8(const float4 u, const float4 v, short8& hi, short8& lo) {
  float f[8] = {u.x, u.y, u.z, u.w, v.x, v.y, v.z, v.w};
#pragma unroll
  for (int i = 0; i < 8; ++i) {
    unsigned short h = bf16_rne(f[i]);
    hi[i] = (short)h;
    float r = f[i] - __uint_as_float((unsigned)h << 16);
    lo[i] = (short)bf16_rne(r);
  }
}

__device__ inline void st8h(f16* p, const float* s) {
  f16 t[8];
#pragma unroll
  for (int i = 0; i < 8; ++i) t[i] = (f16)s[i];
  *(f16x8*)p = *(f16x8*)&t[0];
}
__device__ inline void ld16h(const f16* p, float* d) {
  f16x8 a = *(const f16x8*)p;
  f16x8 b = *(const f16x8*)(p + 8);
#pragma unroll
  for (int i = 0; i < 8; ++i) { d[i] = (float)a[i]; d[8 + i] = (float)b[i]; }
}

// load A2 row; detect arithmetic-progression structure (A2[n]=(n+1)*A2[0])
__device__ inline bool loadA2(const float* A_log, int d, float* A2) {
  const float4* ap = (const float4*)(A_log + (size_t)d * D_ST);
#pragma unroll
  for (int i = 0; i < 4; ++i) {
    float4 a4 = ap[i];
    A2[4 * i + 0] = -__expf(a4.x) * LOG2E;
    A2[4 * i + 1] = -__expf(a4.y) * LOG2E;
    A2[4 * i + 2] = -__expf(a4.z) * LOG2E;
    A2[4 * i + 3] = -__expf(a4.w) * LOG2E;
  }
  bool pw = true;
#pragma unroll
  for (int n = 1; n < 16; ++n) {
    float ref = (float)(n + 1) * A2[0];
    pw = pw && (fabsf(A2[n] - ref) <= 2e-5f * fabsf(ref));
  }
  return pw;
}

// same, but keep only half hf (8 coeffs) + A2[0]; pw check over full row so both
// halves of a lane pair take the same branch.
__device__ inline bool loadA2half(const float* A_log, int d, int hf, float* A2h,
                                  float& a0) {
  const float4* ap = (const float4*)(A_log + (size_t)d * D_ST);
  float t[16];
#pragma unroll
  for (int i = 0; i < 4; ++i) {
    float4 a4 = ap[i];
    t[4 * i + 0] = -__expf(a4.x) * LOG2E;
    t[4 * i + 1] = -__expf(a4.y) * LOG2E;
    t[4 * i + 2] = -__expf(a4.z) * LOG2E;
    t[4 * i + 3] = -__expf(a4.w) * LOG2E;
  }
  a0 = t[0];
  bool pw = true;
#pragma unroll
  for (int n = 1; n < 16; ++n) {
    float ref = (float)(n + 1) * t[0];
    pw = pw && (fabsf(t[n] - ref) <= 2e-5f * fabsf(ref));
  }
#pragma unroll
  for (int k = 0; k < 8; ++k) A2h[k] = t[8 * hf + k];
  return pw;
}

// ---------------- W -> bf16 hi/lo split --------------------------------------
__global__ __launch_bounds__(256) void k_wprep(const float* __restrict__ W,
                                               short* __restrict__ Whi,
                                               short* __restrict__ Wlo) {
  const int i = (blockIdx.x * 256 + threadIdx.x) * 4;
  float4 w = *(const float4*)(W + i);
  float f[4] = {w.x, w.y, w.z, w.w};
  unsigned short h[4], lo[4];
#pragma unroll
  for (int j = 0; j < 4; ++j) {
    h[j] = bf16_rne(f[j]);
    float r = f[j] - __uint_as_float((unsigned)h[j] << 16);
    lo[j] = bf16_rne(r);
  }
  *(uint2*)(Whi + i) = make_uint2(h[0] | ((unsigned)h[1] << 16), h[2] | ((unsigned)h[3] << 16));
  *(uint2*)(Wlo + i) = make_uint2(lo[0] | ((unsigned)lo[1] << 16), lo[2] | ((unsigned)lo[3] << 16));
}

// ---------------- proj = x @ W^T via MFMA bf16x3 (R5-proven) -----------------
#define MM3(ACC, AH, AL, BH, BL)                                        \
  ACC = __builtin_amdgcn_mfma_f32_16x16x32_bf16(AL, BH, ACC, 0, 0, 0);  \
  ACC = __builtin_amdgcn_mfma_f32_16x16x32_bf16(AH, BL, ACC, 0, 0, 0);  \
  ACC = __builtin_amdgcn_mfma_f32_16x16x32_bf16(AH, BH, ACC, 0, 0, 0);

#define LOADB(P, S)                                   \
  {                                                   \
    const int kb = ((S) & 15) * 32;                   \
    P##h0 = *(const short8*)(bh + kb);                \
    P##h1 = *(const short8*)(bh + 8192 + kb);         \
    P##h2 = *(const short8*)(bh + 16384 + kb);        \
    P##h3 = *(const short8*)(bh + 24576 + kb);        \
    P##l0 = *(const short8*)(bl + kb);                \
    P##l1 = *(const short8*)(bl + 8192 + kb);         \
    P##l2 = *(const short8*)(bl + 16384 + kb);        \
    P##l3 = *(const short8*)(bl + 24576 + kb);        \
  }

#define LOADA(Aa, Ab, S)                              \
  {                                                   \
    const int ka = ((S) & 15) * 32;                   \
    Aa = *(const float4*)(xr + ka);                   \
    Ab = *(const float4*)(xr + ka + 4);               \
  }

#define SUBSTEP(Aa, Ab, P, SA, SB)                    \
  {                                                   \
    short8 ahi, alo;                                  \
    cvt8(Aa, Ab, ahi, alo);                           \
    MM3(acc0, ahi, alo, P##h0, P##l0);                \
    MM3(acc1, ahi, alo, P##h1, P##l1);                \
    MM3(acc2, ahi, alo, P##h2, P##l2);                \
    MM3(acc3, ahi, alo, P##h3, P##l3);                \
    LOADB(P, SB);                                     \
    LOADA(Aa, Ab, SA);                                \
  }

__global__ __launch_bounds__(64) void k_proj(const float* __restrict__ x,
                                             const short* __restrict__ Whi,
                                             const short* __restrict__ Wlo,
                                             float* __restrict__ proj) {
  const int row0 = blockIdx.x * 16;
  const int l = threadIdx.x;
  const int m = l & 15;
  const int ko = (l >> 4) * 8;
  const float* xr = x + (size_t)(row0 + m) * D_IN + ko;
  const short* bh = Whi + (size_t)m * D_IN + ko;
  const short* bl = Wlo + (size_t)m * D_IN + ko;

  f32x4 acc0 = {0.f, 0.f, 0.f, 0.f}, acc1 = acc0, acc2 = acc0, acc3 = acc0;
  float4 A0a, A0b, A1a, A1b, A2a, A2b, A3a, A3b;
  short8 Xh0, Xh1, Xh2, Xh3, Xl0, Xl1, Xl2, Xl3;
  short8 Yh0, Yh1, Yh2, Yh3, Yl0, Yl1, Yl2, Yl3;
  LOADA(A0a, A0b, 0); LOADA(A1a, A1b, 1); LOADA(A2a, A2b, 2); LOADA(A3a, A3b, 3);
  LOADB(X, 0); LOADB(Y, 1);

#pragma unroll
  for (int it = 0; it < 4; ++it) {
    const int s = it * 4;
    SUBSTEP(A0a, A0b, X, s + 4, s + 2);
    SUBSTEP(A1a, A1b, Y, s + 5, s + 3);
    SUBSTEP(A2a, A2b, X, s + 6, s + 4);
    SUBSTEP(A3a, A3b, Y, s + 7, s + 5);
  }

  const int r0 = (l >> 4) * 4;
#pragma unroll
  for (int r = 0; r < 4; ++r) {
    float* pr = proj + (size_t)(row0 + r0 + r) * PDIM + m;
    pr[0] = acc0[r]; pr[16] = acc1[r]; pr[32] = acc2[r]; pr[48] = acc3[r];
  }
}

// ---------------- pass 1: dt once, zero-init scan, fp16 state out ------------
// Lane-pair split: d = by*128 + (tid>>1); hf = tid&1 owns states n = 8*hf..8*hf+7.
__global__ __launch_bounds__(256, 4) void k_scan1(const float* __restrict__ x,
                                                  const float* __restrict__ proj,
                                                  const float* __restrict__ A_log,
                                                  const float* __restrict__ W_dt,
                                                  const float* __restrict__ b_dt,
                                                  const float* __restrict__ alpha_p,
                                                  const float* __restrict__ beta_p,
                                                  f16* __restrict__ hh,
                                                  f16* __restrict__ vh,
                                                  f16* __restrict__ cvv,
                                                  float* __restrict__ sdt,
                                                  f16* __restrict__ dth) {
  __shared__ float Ps[LCH][PDIM];
  const int c = blockIdx.x, b = blockIdx.z;
  const int hf = threadIdx.x & 1;
  const int d = blockIdx.y * 128 + (threadIdx.x >> 1);
  const int t0 = c * LCH;
  {
    const float4* src = (const float4*)(proj + ((size_t)b * LSEQ + t0) * PDIM);
    ((float4*)&Ps[0][0])[threadIdx.x] = src[threadIdx.x];
  }
  float xs[LCH];
  {
    const float* xp = x + ((size_t)b * LSEQ + t0) * D_IN + d;
#pragma unroll
    for (int j = 0; j < LCH; ++j) xs[j] = xp[(size_t)j * D_IN];
  }
  const float alpha = alpha_p[0];
  const float beta = 1.f / (1.f + __expf(-beta_p[0]));
  float A2h[8], a0;
  const bool powA = loadA2half(A_log, d, hf, A2h, a0);
  __syncthreads();

  // dt GEMM: computed redundantly by both halves of a lane pair (VALU is idle;
  // keeps dt in registers instead of round-tripping HBM — R15 lesson).
  float dtv[LCH];
  {
    float4 w4[8];
    const float4* wp = (const float4*)(W_dt + (size_t)d * DTR);
#pragma unroll
    for (int i = 0; i < 8; ++i) w4[i] = wp[i];
    const float bb = b_dt[d];
#pragma unroll
    for (int j = 0; j < LCH; ++j) {
      const float4* pj = (const float4*)&Ps[j][0];
      float c0 = bb, c1 = 0.f, c2 = 0.f, c3 = 0.f;
#pragma unroll
      for (int k = 0; k < 8; ++k) {
        float4 p = pj[k];
        c0 = fmaf(p.x, w4[k].x, c0);
        c1 = fmaf(p.y, w4[k].y, c1);
        c2 = fmaf(p.z, w4[k].z, c2);
        c3 = fmaf(p.w, w4[k].w, c3);
      }
      float acc = (c0 + c1) + (c2 + c3);
      float e = fast_exp2(acc * LOG2E);
      dtv[j] = (acc > 20.f) ? acc : LN2 * fast_log2(1.f + e);
    }
  }
  if (hf == 0) {
    f16* dp = dth + ((size_t)b * LSEQ + t0) * D_IN + d;
#pragma unroll
    for (int j = 0; j < LCH; ++j) dp[(size_t)j * D_IN] = (f16)dtv[j];
  }

  float h8[8] = {}, v8[8] = {}, cv8[8] = {};
  float bpow = 1.f, sd = 0.f;
  if (powA) {
#pragma unroll
    for (int j = 0; j < LCH; ++j) {
      const float dtc = dtv[j], xv = xs[j];
      sd += dtc;
      bpow *= beta;
      const float u = alpha * dtc * xv;
      const float r = fast_exp2(dtc * a0);
      float ar = 1.f;
      if (hf) {
        const float r2 = r * r;
        const float r4 = r2 * r2;
        ar = r4 * r4;  // r^8: states 8..15 start at a^(9)
      }
      float4 B0 = *(const float4*)&Ps[j][DTR + 8 * hf];
      float4 B1 = *(const float4*)&Ps[j][DTR + 8 * hf + 4];
      const float Bf[8] = {B0.x, B0.y, B0.z, B0.w, B1.x, B1.y, B1.z, B1.w};
#pragma unroll
      for (int k = 0; k < 8; ++k) {
        ar *= r;
        v8[k] = fmaf(beta, v8[k], u * Bf[k]);
        h8[k] = fmaf(ar, h8[k], v8[k]);
        cv8[k] = fmaf(ar, cv8[k], bpow);
      }
    }
  } else {
#pragma unroll
    for (int j = 0; j < LCH; ++j) {
      const float dtc = dtv[j], xv = xs[j];
      sd += dtc;
      bpow *= beta;
      const float u = alpha * dtc * xv;
      float4 B0 = *(const float4*)&Ps[j][DTR + 8 * hf];
      float4 B1 = *(const float4*)&Ps[j][DTR + 8 * hf + 4];
      const float Bf[8] = {B0.x, B0.y, B0.z, B0.w, B1.x, B1.y, B1.z, B1.w};
#pragma unroll
      for (int k = 0; k < 8; ++k) {
        const float ar = fast_exp2(dtc * A2h[k]);
        v8[k] = fmaf(beta, v8[k], u * Bf[k]);
        h8[k] = fmaf(ar, h8[k], v8[k]);
        cv8[k] = fmaf(ar, cv8[k], bpow);
      }
    }
  }

  const size_t base = ((size_t)(b * NCH + c) * D_IN + d) * D_ST + hf * 8;
  st8h(hh + base, h8);
  st8h(vh + base, v8);
  st8h(cvv + base, cv8);
  if (hf == 0) sdt[(size_t)(b * NCH + c) * D_IN + d] = sd;
}

// ---------------- fixup: scan over 256 chunks; group-8 lookahead -------------
__global__ __launch_bounds__(64) void k_fix(f16* __restrict__ hh,
                                            f16* __restrict__ vh,
                                            const f16* __restrict__ cvv,
                                            const float* __restrict__ sdt,
                                            const float* __restrict__ A_log,
                                            const float* __restrict__ beta_p) {
  const int g = blockIdx.x * 64 + threadIdx.x;  // 16384 = B * D * N
  const int b = g >> 13;
  const int dn = g & 8191;
  const float beta = 1.f / (1.f + __expf(-beta_p[0]));
  const float A2 = -__expf(A_log[dn]) * LOG2E;
  float bL = beta;
#pragma unroll
  for (int i = 0; i < 4; ++i) bL *= bL;  // beta^16 = beta^LCH

  const size_t cs = (size_t)D_IN * D_ST;
  const size_t base = (size_t)b * NCH * cs + dn;
  const size_t sbase = (size_t)b * NCH * D_IN + (dn >> 4);

  float hg[8], vg[8], cg[8], sg[8];
#pragma unroll
  for (int i = 0; i < 8; ++i) {
    hg[i] = (float)hh[base + i * cs];
    vg[i] = (float)vh[base + i * cs];
    cg[i] = (float)cvv[base + i * cs];
    sg[i] = sdt[sbase + i * D_IN];
  }
  float H = 0.f, V = 0.f;
  for (int c0 = 0; c0 < NCH; c0 += 8) {
    const int cp = (c0 + 8) & (NCH - 1);  // wraps; last prefetch unused
    float hn[8], vn[8], cn[8], sn[8];
#pragma unroll
    for (int i = 0; i < 8; ++i) {
      hn[i] = (float)hh[base + (size_t)(cp + i) * cs];
      vn[i] = (float)vh[base + (size_t)(cp + i) * cs];
      cn[i] = (float)cvv[base + (size_t)(cp + i) * cs];
      sn[i] = sdt[sbase + (size_t)(cp + i) * D_IN];
    }
#pragma unroll
    for (int i = 0; i < 8; ++i) {
      hh[base + (size_t)(c0 + i) * cs] = (f16)H;
      vh[base + (size_t)(c0 + i) * cs] = (f16)V;
      const float Pa = fast_exp2(sg[i] * A2);
      const float Hn = fmaf(Pa, H, fmaf(cg[i], V, hg[i]));
      V = fmaf(bL, V, vg[i]);
      H = Hn;
    }
#pragma unroll
    for (int i = 0; i < 8; ++i) { hg[i] = hn[i]; vg[i] = vn[i]; cg[i] = cn[i]; sg[i] = sn[i]; }
  }
}

// ---------------- pass 2: read dt(fp16)+x, correct-init scan, emit y ---------
#define S2_BODY(GET_A)                                        \
  _Pragma("unroll")                                           \
  for (int j = 0; j < LCH; ++j) {                             \
    const float dtc = dtv[j], xv = xs[j];                     \
    const float u = alpha * dtc * xv;                         \
    GET_A;                                                    \
    float4 Bq[8];                                             \
    _Pragma("unroll")                                         \
    for (int i = 0; i < 8; ++i) Bq[i] = ((const float4*)&Ps[j][DTR])[i]; \
    const float* Bf = (const float*)Bq;                       \
    float y0 = 0.f, y1 = 0.f, y2 = 0.f, y3 = 0.f;             \
    float ar = 1.f;                                           \
    _Pragma("unroll")                                         \
    for (int n = 0; n < 16; ++n) {                            \
      NEXT_A(ar, n);                                          \
      v[n] = fmaf(beta, v[n], u * Bf[n]);                     \
      h[n] = fmaf(ar, h[n], v[n]);                            \
      float hc = h[n] * Bf[16 + n];                           \
      if ((n & 3) == 0) y0 += hc;                             \
      else if ((n & 3) == 1) y1 += hc;                        \
      else if ((n & 3) == 2) y2 += hc;                        \
      else y3 += hc;                                          \
    }                                                         \
    op[(size_t)j * D_IN] = (y0 + y1) + (y2 + y3) + Dv * xv;   \
  }

__global__ __launch_bounds__(256) void k_scan2(const float* __restrict__ x,
                                               const f16* __restrict__ dth,
                                               const float* __restrict__ proj,
                                               const float* __restrict__ A_log,
                                               const float* __restrict__ D_param,
                                               const float* __restrict__ alpha_p,
                                               const float* __restrict__ beta_p,
                                               const f16* __restrict__ hh,
                                               const f16* __restrict__ vh,
                                               float* __restrict__ out) {
  __shared__ float Ps[LCH][PDIM];
  const int c = blockIdx.x, b = blockIdx.z;
  const int d = blockIdx.y * 256 + threadIdx.x;
  const int t0 = c * LCH;
  {
    const float4* src = (const float4*)(proj + ((size_t)b * LSEQ + t0) * PDIM);
    ((float4*)&Ps[0][0])[threadIdx.x] = src[threadIdx.x];
  }
  float xs[LCH], dtv[LCH];
  {
    const float* xp = x + ((size_t)b * LSEQ + t0) * D_IN + d;
    const f16* dp = dth + ((size_t)b * LSEQ + t0) * D_IN + d;
#pragma unroll
    for (int j = 0; j < LCH; ++j) xs[j] = xp[(size_t)j * D_IN];
#pragma unroll
    for (int j = 0; j < LCH; ++j) dtv[j] = (float)dp[(size_t)j * D_IN];
  }
  const float alpha = alpha_p[0];
  const float beta = 1.f / (1.f + __expf(-beta_p[0]));
  const float Dv = D_param[d];
  float A2[D_ST];
  const bool powA = loadA2(A_log, d, A2);
  const size_t ibase = ((size_t)(b * NCH + c) * D_IN + d) * D_ST;
  float h[16], v[16];
  ld16h(hh + ibase, h);
  ld16h(vh + ibase, v);
  __syncthreads();

  float* op = out + ((size_t)b * LSEQ + t0) * D_IN + d;
  if (powA) {
#define NEXT_A(ar, n) ar *= r
    S2_BODY(const float r = fast_exp2(dtc * A2[0]))
#undef NEXT_A
  } else {
#define NEXT_A(ar, n) ar = fast_exp2(dtc * A2[n])
    S2_BODY()
#undef NEXT_A
  }
}

extern "C" void kernel_launch(void* const* d_in, const int* in_sizes, int n_in,
                              void* d_out, int out_size, void* d_ws, size_t ws_size,
                              hipStream_t stream) {
  const float* x = (const float*)d_in[0];
  const float* A_log = (const float*)d_in[1];
  const float* D_param = (const float*)d_in[2];
  const float* W_xproj = (const float*)d_in[3];
  const float* W_dt = (const float*)d_in[4];
  const float* b_dt = (const float*)d_in[5];
  const float* alpha = (const float*)d_in[6];
  const float* beta_logit = (const float*)d_in[7];
  float* out = (float*)d_out;

  const size_t NST = (size_t)BSZ * NCH * D_IN * D_ST;  // 4194304
  float* ws = (float*)d_ws;
  float* proj = ws;                                  // 524288 floats
  float* sdt = proj + (size_t)BSZ * LSEQ * PDIM;     // 262144 floats
  f16* hh = (f16*)(sdt + (size_t)BSZ * NCH * D_IN);  // 4194304 halves
  f16* vh = hh + NST;
  f16* cvv = vh + NST;
  f16* dth = cvv + NST;                              // B*L*D halves
  short* Whi = (short*)(dth + (size_t)BSZ * LSEQ * D_IN);
  short* Wlo = Whi + (size_t)PDIM * D_IN;            // total ~37 MB

  k_wprep<<<dim3(PDIM * D_IN / 1024), dim3(256), 0, stream>>>(W_xproj, Whi, Wlo);
  k_proj<<<dim3(BSZ * LSEQ / 16), dim3(64), 0, stream>>>(x, Whi, Wlo, proj);
  k_scan1<<<dim3(NCH, D_IN / 128, BSZ), dim3(256), 0, stream>>>(
      x, proj, A_log, W_dt, b_dt, alpha, beta_logit, hh, vh, cvv, sdt, dth);
  k_fix<<<dim3(BSZ * D_IN * D_ST / 64), dim3(64), 0, stream>>>(hh, vh, cvv, sdt, A_log,
                                                               beta_logit);
  k_scan2<<<dim3(NCH, D_IN / 256, BSZ), dim3(256), 0, stream>>>(
      x, dth, proj, A_log, D_param, alpha, beta_logit, hh, vh, out);
}

// Round 3
// 176.003 us; speedup vs baseline: 1.1893x; 1.1843x over previous
//
#include <hip/hip_runtime.h>

// MomentumSSM B=2, L=4096, D=512, N=16, R=32, P=64 — chunk-parallel scan, NCH=256.
// R17: R12 structure (5 dispatches) + scan1 lane-pair split, spill/alloca-clean.
//   k_wprep -> k_proj (MFMA bf16x3) -> k_scan1 -> k_fix -> k_scan2
// - scan1: lane pair per d-channel (tid&1 = state half, 8 states each); dt dot
//   K-split across the pair + one shfl_xor per step (no dtv array, w4 = 16 regs).
//   All private arrays STATIC-indexed. Plain __launch_bounds__(256).
// - hh/vh/cvv/sdt/dth layouts BIT-IDENTICAL to R12 -> k_fix/k_scan2 untouched (R12 code).
// TOOLCHAIN LANDMINES (measured R15/R16):
//   * __launch_bounds__(256, 4) caps VGPR at 64 (not 128) -> scratch spills:
//     scan1 WRITE_SIZE 34->97/169 MB. Never use the min-waves arg here.
//   * runtime-indexed private array (t[8*hf+k]) -> promote-alloca-to-LDS:
//     LDS 4096->20480, SQ_LDS_BANK_CONFLICT 0->983K. Static indices only.
//   * materializing dt through HBM between kernels (R15 k_dt): +37us net loss.
// Disproven: coop launch, manual grid barrier (~80us/sync), dt recompute in scan2.
//
// v_t = beta*v + alpha*inp ; h_t = a_t*h + v ; a_t = exp(dt*A_n)
// chunk map: h_end = Pa*H0 + cv*V0 + hhat ; v_end = beta^LCH*V0 + vhat

#define D_IN 512
#define D_ST 16
#define DTR  32
#define BSZ  2
#define LSEQ 4096
#define PDIM 64
#define NCH  256
#define LCH  (LSEQ / NCH)  // 16
#define LOG2E 1.44269504f
#define LN2   0.69314718f

typedef __attribute__((ext_vector_type(8))) short short8;
typedef __attribute__((ext_vector_type(4))) float f32x4;
typedef _Float16 f16;
typedef __attribute__((ext_vector_type(8))) _Float16 f16x8;

__device__ inline float fast_exp2(float x) { return __builtin_amdgcn_exp2f(x); }
__device__ inline float fast_log2(float x) { return __builtin_amdgcn_logf(x); }

__device__ inline unsigned short bf16_rne(float f) {
  unsigned b = __float_as_uint(f);
  return (unsigned short)((b + 0x7fffu + ((b >> 16) & 1u)) >> 16);
}

__device__ inline void cvt8(const float4 u, const float4 v, short8& hi, short8& lo) {
  float f[8] = {u.x, u.y, u.z, u.w, v.x, v.y, v.z, v.w};
#pragma unroll
  for (int i = 0; i < 8; ++i) {
    unsigned short h = bf16_rne(f[i]);
    hi[i] = (short)h;
    float r = f[i] - __uint_as_float((unsigned)h << 16);
    lo[i] = (short)bf16_rne(r);
  }
}

__device__ inline void st8h(f16* p, const float* s) {
  f16 t[8];
#pragma unroll
  for (int i = 0; i < 8; ++i) t[i] = (f16)s[i];
  *(f16x8*)p = *(f16x8*)&t[0];
}
__device__ inline void ld16h(const f16* p, float* d) {
  f16x8 a = *(const f16x8*)p;
  f16x8 b = *(const f16x8*)(p + 8);
#pragma unroll
  for (int i = 0; i < 8; ++i) { d[i] = (float)a[i]; d[8 + i] = (float)b[i]; }
}

// load A2 row; detect arithmetic-progression structure (A2[n]=(n+1)*A2[0])
__device__ inline bool loadA2(const float* A_log, int d, float* A2) {
  const float4* ap = (const float4*)(A_log + (size_t)d * D_ST);
#pragma unroll
  for (int i = 0; i < 4; ++i) {
    float4 a4 = ap[i];
    A2[4 * i + 0] = -__expf(a4.x) * LOG2E;
    A2[4 * i + 1] = -__expf(a4.y) * LOG2E;
    A2[4 * i + 2] = -__expf(a4.z) * LOG2E;
    A2[4 * i + 3] = -__expf(a4.w) * LOG2E;
  }
  bool pw = true;
#pragma unroll
  for (int n = 1; n < 16; ++n) {
    float ref = (float)(n + 1) * A2[0];
    pw = pw && (fabsf(A2[n] - ref) <= 2e-5f * fabsf(ref));
  }
  return pw;
}

// ---------------- W -> bf16 hi/lo split --------------------------------------
__global__ __launch_bounds__(256) void k_wprep(const float* __restrict__ W,
                                               short* __restrict__ Whi,
                                               short* __restrict__ Wlo) {
  const int i = (blockIdx.x * 256 + threadIdx.x) * 4;
  float4 w = *(const float4*)(W + i);
  float f[4] = {w.x, w.y, w.z, w.w};
  unsigned short h[4], lo[4];
#pragma unroll
  for (int j = 0; j < 4; ++j) {
    h[j] = bf16_rne(f[j]);
    float r = f[j] - __uint_as_float((unsigned)h[j] << 16);
    lo[j] = bf16_rne(r);
  }
  *(uint2*)(Whi + i) = make_uint2(h[0] | ((unsigned)h[1] << 16), h[2] | ((unsigned)h[3] << 16));
  *(uint2*)(Wlo + i) = make_uint2(lo[0] | ((unsigned)lo[1] << 16), lo[2] | ((unsigned)lo[3] << 16));
}

// ---------------- proj = x @ W^T via MFMA bf16x3 (R5-proven) -----------------
#define MM3(ACC, AH, AL, BH, BL)                                        \
  ACC = __builtin_amdgcn_mfma_f32_16x16x32_bf16(AL, BH, ACC, 0, 0, 0);  \
  ACC = __builtin_amdgcn_mfma_f32_16x16x32_bf16(AH, BL, ACC, 0, 0, 0);  \
  ACC = __builtin_amdgcn_mfma_f32_16x16x32_bf16(AH, BH, ACC, 0, 0, 0);

#define LOADB(P, S)                                   \
  {                                                   \
    const int kb = ((S) & 15) * 32;                   \
    P##h0 = *(const short8*)(bh + kb);                \
    P##h1 = *(const short8*)(bh + 8192 + kb);         \
    P##h2 = *(const short8*)(bh + 16384 + kb);        \
    P##h3 = *(const short8*)(bh + 24576 + kb);        \
    P##l0 = *(const short8*)(bl + kb);                \
    P##l1 = *(const short8*)(bl + 8192 + kb);         \
    P##l2 = *(const short8*)(bl + 16384 + kb);        \
    P##l3 = *(const short8*)(bl + 24576 + kb);        \
  }

#define LOADA(Aa, Ab, S)                              \
  {                                                   \
    const int ka = ((S) & 15) * 32;                   \
    Aa = *(const float4*)(xr + ka);                   \
    Ab = *(const float4*)(xr + ka + 4);               \
  }

#define SUBSTEP(Aa, Ab, P, SA, SB)                    \
  {                                                   \
    short8 ahi, alo;                                  \
    cvt8(Aa, Ab, ahi, alo);                           \
    MM3(acc0, ahi, alo, P##h0, P##l0);                \
    MM3(acc1, ahi, alo, P##h1, P##l1);                \
    MM3(acc2, ahi, alo, P##h2, P##l2);                \
    MM3(acc3, ahi, alo, P##h3, P##l3);                \
    LOADB(P, SB);                                     \
    LOADA(Aa, Ab, SA);                                \
  }

__global__ __launch_bounds__(64) void k_proj(const float* __restrict__ x,
                                             const short* __restrict__ Whi,
                                             const short* __restrict__ Wlo,
                                             float* __restrict__ proj) {
  const int row0 = blockIdx.x * 16;
  const int l = threadIdx.x;
  const int m = l & 15;
  const int ko = (l >> 4) * 8;
  const float* xr = x + (size_t)(row0 + m) * D_IN + ko;
  const short* bh = Whi + (size_t)m * D_IN + ko;
  const short* bl = Wlo + (size_t)m * D_IN + ko;

  f32x4 acc0 = {0.f, 0.f, 0.f, 0.f}, acc1 = acc0, acc2 = acc0, acc3 = acc0;
  float4 A0a, A0b, A1a, A1b, A2a, A2b, A3a, A3b;
  short8 Xh0, Xh1, Xh2, Xh3, Xl0, Xl1, Xl2, Xl3;
  short8 Yh0, Yh1, Yh2, Yh3, Yl0, Yl1, Yl2, Yl3;
  LOADA(A0a, A0b, 0); LOADA(A1a, A1b, 1); LOADA(A2a, A2b, 2); LOADA(A3a, A3b, 3);
  LOADB(X, 0); LOADB(Y, 1);

#pragma unroll
  for (int it = 0; it < 4; ++it) {
    const int s = it * 4;
    SUBSTEP(A0a, A0b, X, s + 4, s + 2);
    SUBSTEP(A1a, A1b, Y, s + 5, s + 3);
    SUBSTEP(A2a, A2b, X, s + 6, s + 4);
    SUBSTEP(A3a, A3b, Y, s + 7, s + 5);
  }

  const int r0 = (l >> 4) * 4;
#pragma unroll
  for (int r = 0; r < 4; ++r) {
    float* pr = proj + (size_t)(row0 + r0 + r) * PDIM + m;
    pr[0] = acc0[r]; pr[16] = acc1[r]; pr[32] = acc2[r]; pr[48] = acc3[r];
  }
}

// ---------------- pass 1: lane-pair scan, on-the-fly dt, fp16 state out ------
// d = by*128 + (tid>>1); hf = tid&1 owns states n = 8*hf..8*hf+7.
// dt dot K-split: lane hf sums k = 16*hf..16*hf+15, combined via shfl_xor(.,1).

#define PWCHK(val, n)                                                        \
  pw = pw && (fabsf((val) - (float)((n) + 1) * a0) <=                        \
              2e-5f * fabsf((float)((n) + 1) * a0));

#define S1_LOOP                                                              \
  _Pragma("unroll")                                                          \
  for (int j = 0; j < LCH; ++j) {                                            \
    const float4* pj = (const float4*)&Ps[j][16 * hf];                       \
    float c0 = 0.f, c1 = 0.f, c2 = 0.f, c3 = 0.f;                            \
    _Pragma("unroll")                                                        \
    for (int k = 0; k < 4; ++k) {                                            \
      float4 p = pj[k];                                                      \
      c0 = fmaf(p.x, w4[k].x, c0);                                           \
      c1 = fmaf(p.y, w4[k].y, c1);                                           \
      c2 = fmaf(p.z, w4[k].z, c2);                                           \
      c3 = fmaf(p.w, w4[k].w, c3);                                           \
    }                                                                        \
    const float part = (c0 + c1) + (c2 + c3);                                \
    const float acc = part + __shfl_xor(part, 1, 64) + bb;                   \
    const float ee = fast_exp2(acc * LOG2E);                                 \
    const float dtc = (acc > 20.f) ? acc : LN2 * fast_log2(1.f + ee);        \
    if (hf == 0) dp[(size_t)j * D_IN] = (f16)dtc;                            \
    sd += dtc;                                                               \
    bpow *= beta;                                                            \
    const float xv = xs[j];                                                  \
    const float u = alpha * dtc * xv;                                        \
    float4 B0 = *(const float4*)&Ps[j][DTR + 8 * hf];                        \
    float4 B1 = *(const float4*)&Ps[j][DTR + 8 * hf + 4];                    \
    const float Bf[8] = {B0.x, B0.y, B0.z, B0.w, B1.x, B1.y, B1.z, B1.w};    \
    AR_INIT;                                                                 \
    _Pragma("unroll")                                                        \
    for (int k = 0; k < 8; ++k) {                                            \
      AR_STEP;                                                               \
      v8[k] = fmaf(beta, v8[k], u * Bf[k]);                                  \
      h8[k] = fmaf(ar, h8[k], v8[k]);                                        \
      cv8[k] = fmaf(ar, cv8[k], bpow);                                       \
    }                                                                        \
  }

__global__ __launch_bounds__(256) void k_scan1(const float* __restrict__ x,
                                               const float* __restrict__ proj,
                                               const float* __restrict__ A_log,
                                               const float* __restrict__ W_dt,
                                               const float* __restrict__ b_dt,
                                               const float* __restrict__ alpha_p,
                                               const float* __restrict__ beta_p,
                                               f16* __restrict__ hh,
                                               f16* __restrict__ vh,
                                               f16* __restrict__ cvv,
                                               float* __restrict__ sdt,
                                               f16* __restrict__ dth) {
  __shared__ float Ps[LCH][PDIM];
  const int c = blockIdx.x, b = blockIdx.z;
  const int hf = threadIdx.x & 1;
  const int d = blockIdx.y * 128 + (threadIdx.x >> 1);
  const int t0 = c * LCH;
  {
    const float4* src = (const float4*)(proj + ((size_t)b * LSEQ + t0) * PDIM);
    ((float4*)&Ps[0][0])[threadIdx.x] = src[threadIdx.x];
  }
  float xs[LCH];
  {
    const float* xp = x + ((size_t)b * LSEQ + t0) * D_IN + d;
#pragma unroll
    for (int j = 0; j < LCH; ++j) xs[j] = xp[(size_t)j * D_IN];
  }
  // K-half of W_dt for this lane (16 regs, not 32)
  float4 w4[4];
  {
    const float4* wp = (const float4*)(W_dt + (size_t)d * DTR + 16 * hf);
#pragma unroll
    for (int i = 0; i < 4; ++i) w4[i] = wp[i];
  }
  const float bb = b_dt[d];
  const float alpha = alpha_p[0];
  const float beta = 1.f / (1.f + __expf(-beta_p[0]));

  // A2 row — STATIC indexing only (named float4s + hf-select)
  float4 e0, e1, e2, e3;
  {
    const float4* ap = (const float4*)(A_log + (size_t)d * D_ST);
    float4 r0 = ap[0], r1 = ap[1], r2 = ap[2], r3 = ap[3];
    e0 = make_float4(-__expf(r0.x) * LOG2E, -__expf(r0.y) * LOG2E,
                     -__expf(r0.z) * LOG2E, -__expf(r0.w) * LOG2E);
    e1 = make_float4(-__expf(r1.x) * LOG2E, -__expf(r1.y) * LOG2E,
                     -__expf(r1.z) * LOG2E, -__expf(r1.w) * LOG2E);
    e2 = make_float4(-__expf(r2.x) * LOG2E, -__expf(r2.y) * LOG2E,
                     -__expf(r2.z) * LOG2E, -__expf(r2.w) * LOG2E);
    e3 = make_float4(-__expf(r3.x) * LOG2E, -__expf(r3.y) * LOG2E,
                     -__expf(r3.z) * LOG2E, -__expf(r3.w) * LOG2E);
  }
  const float a0 = e0.x;
  bool pw = true;
  PWCHK(e0.y, 1) PWCHK(e0.z, 2) PWCHK(e0.w, 3)
  PWCHK(e1.x, 4) PWCHK(e1.y, 5) PWCHK(e1.z, 6) PWCHK(e1.w, 7)
  PWCHK(e2.x, 8) PWCHK(e2.y, 9) PWCHK(e2.z, 10) PWCHK(e2.w, 11)
  PWCHK(e3.x, 12) PWCHK(e3.y, 13) PWCHK(e3.z, 14) PWCHK(e3.w, 15)
  float A2h[8];  // static writes/reads only
  {
    float4 u0 = hf ? e2 : e0;
    float4 u1 = hf ? e3 : e1;
    A2h[0] = u0.x; A2h[1] = u0.y; A2h[2] = u0.z; A2h[3] = u0.w;
    A2h[4] = u1.x; A2h[5] = u1.y; A2h[6] = u1.z; A2h[7] = u1.w;
  }
  __syncthreads();

  f16* dp = dth + ((size_t)b * LSEQ + t0) * D_IN + d;
  float h8[8] = {}, v8[8] = {}, cv8[8] = {};
  float bpow = 1.f, sd = 0.f;

  if (pw) {
#define AR_INIT                                                   \
    const float r = fast_exp2(dtc * a0);                          \
    const float r2 = r * r;                                       \
    const float r4 = r2 * r2;                                     \
    float ar = hf ? r4 * r4 : 1.f
#define AR_STEP ar *= r
    S1_LOOP
#undef AR_INIT
#undef AR_STEP
  } else {
#define AR_INIT float ar
#define AR_STEP ar = fast_exp2(dtc * A2h[k])
    S1_LOOP
#undef AR_INIT
#undef AR_STEP
  }

  const size_t base = ((size_t)(b * NCH + c) * D_IN + d) * D_ST + hf * 8;
  st8h(hh + base, h8);
  st8h(vh + base, v8);
  st8h(cvv + base, cv8);
  if (hf == 0) sdt[(size_t)(b * NCH + c) * D_IN + d] = sd;
}

// ---------------- fixup: scan over 256 chunks; group-8 lookahead -------------
__global__ __launch_bounds__(64) void k_fix(f16* __restrict__ hh,
                                            f16* __restrict__ vh,
                                            const f16* __restrict__ cvv,
                                            const float* __restrict__ sdt,
                                            const float* __restrict__ A_log,
                                            const float* __restrict__ beta_p) {
  const int g = blockIdx.x * 64 + threadIdx.x;  // 16384 = B * D * N
  const int b = g >> 13;
  const int dn = g & 8191;
  const float beta = 1.f / (1.f + __expf(-beta_p[0]));
  const float A2 = -__expf(A_log[dn]) * LOG2E;
  float bL = beta;
#pragma unroll
  for (int i = 0; i < 4; ++i) bL *= bL;  // beta^16 = beta^LCH

  const size_t cs = (size_t)D_IN * D_ST;
  const size_t base = (size_t)b * NCH * cs + dn;
  const size_t sbase = (size_t)b * NCH * D_IN + (dn >> 4);

  float hg[8], vg[8], cg[8], sg[8];
#pragma unroll
  for (int i = 0; i < 8; ++i) {
    hg[i] = (float)hh[base + i * cs];
    vg[i] = (float)vh[base + i * cs];
    cg[i] = (float)cvv[base + i * cs];
    sg[i] = sdt[sbase + i * D_IN];
  }
  float H = 0.f, V = 0.f;
  for (int c0 = 0; c0 < NCH; c0 += 8) {
    const int cp = (c0 + 8) & (NCH - 1);  // wraps; last prefetch unused
    float hn[8], vn[8], cn[8], sn[8];
#pragma unroll
    for (int i = 0; i < 8; ++i) {
      hn[i] = (float)hh[base + (size_t)(cp + i) * cs];
      vn[i] = (float)vh[base + (size_t)(cp + i) * cs];
      cn[i] = (float)cvv[base + (size_t)(cp + i) * cs];
      sn[i] = sdt[sbase + (size_t)(cp + i) * D_IN];
    }
#pragma unroll
    for (int i = 0; i < 8; ++i) {
      hh[base + (size_t)(c0 + i) * cs] = (f16)H;
      vh[base + (size_t)(c0 + i) * cs] = (f16)V;
      const float Pa = fast_exp2(sg[i] * A2);
      const float Hn = fmaf(Pa, H, fmaf(cg[i], V, hg[i]));
      V = fmaf(bL, V, vg[i]);
      H = Hn;
    }
#pragma unroll
    for (int i = 0; i < 8; ++i) { hg[i] = hn[i]; vg[i] = vn[i]; cg[i] = cn[i]; sg[i] = sn[i]; }
  }
}

// ---------------- pass 2: read dt(fp16)+x, correct-init scan, emit y ---------
#define S2_BODY(GET_A)                                        \
  _Pragma("unroll")                                           \
  for (int j = 0; j < LCH; ++j) {                             \
    const float dtc = dtv[j], xv = xs[j];                     \
    const float u = alpha * dtc * xv;                         \
    GET_A;                                                    \
    float4 Bq[8];                                             \
    _Pragma("unroll")                                         \
    for (int i = 0; i < 8; ++i) Bq[i] = ((const float4*)&Ps[j][DTR])[i]; \
    const float* Bf = (const float*)Bq;                       \
    float y0 = 0.f, y1 = 0.f, y2 = 0.f, y3 = 0.f;             \
    float ar = 1.f;                                           \
    _Pragma("unroll")                                         \
    for (int n = 0; n < 16; ++n) {                            \
      NEXT_A(ar, n);                                          \
      v[n] = fmaf(beta, v[n], u * Bf[n]);                     \
      h[n] = fmaf(ar, h[n], v[n]);                            \
      float hc = h[n] * Bf[16 + n];                           \
      if ((n & 3) == 0) y0 += hc;                             \
      else if ((n & 3) == 1) y1 += hc;                        \
      else if ((n & 3) == 2) y2 += hc;                        \
      else y3 += hc;                                          \
    }                                                         \
    op[(size_t)j * D_IN] = (y0 + y1) + (y2 + y3) + Dv * xv;   \
  }

__global__ __launch_bounds__(256) void k_scan2(const float* __restrict__ x,
                                               const f16* __restrict__ dth,
                                               const float* __restrict__ proj,
                                               const float* __restrict__ A_log,
                                               const float* __restrict__ D_param,
                                               const float* __restrict__ alpha_p,
                                               const float* __restrict__ beta_p,
                                               const f16* __restrict__ hh,
                                               const f16* __restrict__ vh,
                                               float* __restrict__ out) {
  __shared__ float Ps[LCH][PDIM];
  const int c = blockIdx.x, b = blockIdx.z;
  const int d = blockIdx.y * 256 + threadIdx.x;
  const int t0 = c * LCH;
  {
    const float4* src = (const float4*)(proj + ((size_t)b * LSEQ + t0) * PDIM);
    ((float4*)&Ps[0][0])[threadIdx.x] = src[threadIdx.x];
  }
  float xs[LCH], dtv[LCH];
  {
    const float* xp = x + ((size_t)b * LSEQ + t0) * D_IN + d;
    const f16* dp = dth + ((size_t)b * LSEQ + t0) * D_IN + d;
#pragma unroll
    for (int j = 0; j < LCH; ++j) xs[j] = xp[(size_t)j * D_IN];
#pragma unroll
    for (int j = 0; j < LCH; ++j) dtv[j] = (float)dp[(size_t)j * D_IN];
  }
  const float alpha = alpha_p[0];
  const float beta = 1.f / (1.f + __expf(-beta_p[0]));
  const float Dv = D_param[d];
  float A2[D_ST];
  const bool powA = loadA2(A_log, d, A2);
  const size_t ibase = ((size_t)(b * NCH + c) * D_IN + d) * D_ST;
  float h[16], v[16];
  ld16h(hh + ibase, h);
  ld16h(vh + ibase, v);
  __syncthreads();

  float* op = out + ((size_t)b * LSEQ + t0) * D_IN + d;
  if (powA) {
#define NEXT_A(ar, n) ar *= r
    S2_BODY(const float r = fast_exp2(dtc * A2[0]))
#undef NEXT_A
  } else {
#define NEXT_A(ar, n) ar = fast_exp2(dtc * A2[n])
    S2_BODY()
#undef NEXT_A
  }
}

extern "C" void kernel_launch(void* const* d_in, const int* in_sizes, int n_in,
                              void* d_out, int out_size, void* d_ws, size_t ws_size,
                              hipStream_t stream) {
  const float* x = (const float*)d_in[0];
  const float* A_log = (const float*)d_in[1];
  const float* D_param = (const float*)d_in[2];
  const float* W_xproj = (const float*)d_in[3];
  const float* W_dt = (const float*)d_in[4];
  const float* b_dt = (const float*)d_in[5];
  const float* alpha = (const float*)d_in[6];
  const float* beta_logit = (const float*)d_in[7];
  float* out = (float*)d_out;

  const size_t NST = (size_t)BSZ * NCH * D_IN * D_ST;  // 4194304
  float* ws = (float*)d_ws;
  float* proj = ws;                                  // 524288 floats
  float* sdt = proj + (size_t)BSZ * LSEQ * PDIM;     // 262144 floats
  f16* hh = (f16*)(sdt + (size_t)BSZ * NCH * D_IN);  // 4194304 halves
  f16* vh = hh + NST;
  f16* cvv = vh + NST;
  f16* dth = cvv + NST;                              // B*L*D halves
  short* Whi = (short*)(dth + (size_t)BSZ * LSEQ * D_IN);
  short* Wlo = Whi + (size_t)PDIM * D_IN;            // total ~37 MB

  k_wprep<<<dim3(PDIM * D_IN / 1024), dim3(256), 0, stream>>>(W_xproj, Whi, Wlo);
  k_proj<<<dim3(BSZ * LSEQ / 16), dim3(64), 0, stream>>>(x, Whi, Wlo, proj);
  k_scan1<<<dim3(NCH, D_IN / 128, BSZ), dim3(256), 0, stream>>>(
      x, proj, A_log, W_dt, b_dt, alpha, beta_logit, hh, vh, cvv, sdt, dth);
  k_fix<<<dim3(BSZ * D_IN * D_ST / 64), dim3(64), 0, stream>>>(hh, vh, cvv, sdt, A_log,
                                                               beta_logit);
  k_scan2<<<dim3(NCH, D_IN / 256, BSZ), dim3(256), 0, stream>>>(
      x, dth, proj, A_log, D_param, alpha, beta_logit, hh, vh, out);
}

// Round 4
// 175.875 us; speedup vs baseline: 1.1902x; 1.0007x over previous
//
#include <hip/hip_runtime.h>

// MomentumSSM B=2, L=4096, D=512, N=16, R=32, P=64 — chunk-parallel scan, NCH=256.
// R18: R12 structure (5 dispatches) with LDS ELIMINATED from both scans.
//   k_wprep -> k_proj (MFMA bf16x3) -> k_scan1 -> k_fix -> k_scan2
// - KEY: all Ps data (proj rows: dt-input, B, C) is wave-uniform (depends on t, not d).
//   Read it via block-uniform global pointers -> s_load (SMEM pipe, SGPRs) instead of
//   staging through LDS (ds_read pipe ~12cyc/b128 x 128-192 reads/thread was ~10-15us
//   of per-CU pipe time per scan). No __syncthreads left; waves fully independent.
// - scan1: dt computed inline (no dtv[16] array); dth/hh/vh/cvv/sdt layouts unchanged.
// - scan2: Bf/Cf now SGPR-resident -> VGPR ~132 -> ~100 (5 waves/SIMD).
// TOOLCHAIN LANDMINES (measured R15/R16):
//   * __launch_bounds__(256, 4) caps VGPR at 64 (not 128) -> scratch spills. Never.
//   * runtime-indexed private arrays -> promote-alloca-to-LDS + bank conflicts.
//     Arrays OK only with fully-unrolled constant-index access.
//   * materializing dt through HBM between kernels (R15 k_dt): +37us net loss.
// Disproven: coop launch, manual grid barrier (~80us/sync), dt recompute in scan2,
// scan1 lane-pair state split (R17: neutral — wave count was not the bottleneck).
//
// v_t = beta*v + alpha*inp ; h_t = a_t*h + v ; a_t = exp(dt*A_n)
// chunk map: h_end = Pa*H0 + cv*V0 + hhat ; v_end = beta^LCH*V0 + vhat

#define D_IN 512
#define D_ST 16
#define DTR  32
#define BSZ  2
#define LSEQ 4096
#define PDIM 64
#define NCH  256
#define LCH  (LSEQ / NCH)  // 16
#define LOG2E 1.44269504f
#define LN2   0.69314718f

typedef __attribute__((ext_vector_type(8))) short short8;
typedef __attribute__((ext_vector_type(4))) float f32x4;
typedef _Float16 f16;
typedef __attribute__((ext_vector_type(8))) _Float16 f16x8;

__device__ inline float fast_exp2(float x) { return __builtin_amdgcn_exp2f(x); }
__device__ inline float fast_log2(float x) { return __builtin_amdgcn_logf(x); }

__device__ inline unsigned short bf16_rne(float f) {
  unsigned b = __float_as_uint(f);
  return (unsigned short)((b + 0x7fffu + ((b >> 16) & 1u)) >> 16);
}

__device__ inline void cvt8(const float4 u, const float4 v, short8& hi, short8& lo) {
  float f[8] = {u.x, u.y, u.z, u.w, v.x, v.y, v.z, v.w};
#pragma unroll
  for (int i = 0; i < 8; ++i) {
    unsigned short h = bf16_rne(f[i]);
    hi[i] = (short)h;
    float r = f[i] - __uint_as_float((unsigned)h << 16);
    lo[i] = (short)bf16_rne(r);
  }
}

__device__ inline void st16h(f16* p, const float* s) {
  f16 t[16];
#pragma unroll
  for (int i = 0; i < 16; ++i) t[i] = (f16)s[i];
  *(f16x8*)p = *(f16x8*)&t[0];
  *(f16x8*)(p + 8) = *(f16x8*)&t[8];
}
__device__ inline void ld16h(const f16* p, float* d) {
  f16x8 a = *(const f16x8*)p;
  f16x8 b = *(const f16x8*)(p + 8);
#pragma unroll
  for (int i = 0; i < 8; ++i) { d[i] = (float)a[i]; d[8 + i] = (float)b[i]; }
}

// pw check: A2[n] = -exp(A_log[d][n])*LOG2E is an arithmetic progression
// (A2[n]=(n+1)*A2[0]). Computes a0 and the predicate; values are transient.
#define PWCHK(val, n)                                                        \
  pw = pw && (fabsf((val) - (float)((n) + 1) * a0) <=                        \
              2e-5f * fabsf((float)((n) + 1) * a0));

__device__ inline bool detectA2(const float* __restrict__ A_log, int d, float& a0) {
  const float4* ap = (const float4*)(A_log + (size_t)d * D_ST);
  float4 r0 = ap[0], r1 = ap[1], r2 = ap[2], r3 = ap[3];
  float4 e0 = make_float4(-__expf(r0.x) * LOG2E, -__expf(r0.y) * LOG2E,
                          -__expf(r0.z) * LOG2E, -__expf(r0.w) * LOG2E);
  float4 e1 = make_float4(-__expf(r1.x) * LOG2E, -__expf(r1.y) * LOG2E,
                          -__expf(r1.z) * LOG2E, -__expf(r1.w) * LOG2E);
  float4 e2 = make_float4(-__expf(r2.x) * LOG2E, -__expf(r2.y) * LOG2E,
                          -__expf(r2.z) * LOG2E, -__expf(r2.w) * LOG2E);
  float4 e3 = make_float4(-__expf(r3.x) * LOG2E, -__expf(r3.y) * LOG2E,
                          -__expf(r3.z) * LOG2E, -__expf(r3.w) * LOG2E);
  a0 = e0.x;
  bool pw = true;
  PWCHK(e0.y, 1) PWCHK(e0.z, 2) PWCHK(e0.w, 3)
  PWCHK(e1.x, 4) PWCHK(e1.y, 5) PWCHK(e1.z, 6) PWCHK(e1.w, 7)
  PWCHK(e2.x, 8) PWCHK(e2.y, 9) PWCHK(e2.z, 10) PWCHK(e2.w, 11)
  PWCHK(e3.x, 12) PWCHK(e3.y, 13) PWCHK(e3.z, 14) PWCHK(e3.w, 15)
  return pw;
}

// ---------------- W -> bf16 hi/lo split --------------------------------------
__global__ __launch_bounds__(256) void k_wprep(const float* __restrict__ W,
                                               short* __restrict__ Whi,
                                               short* __restrict__ Wlo) {
  const int i = (blockIdx.x * 256 + threadIdx.x) * 4;
  float4 w = *(const float4*)(W + i);
  float f[4] = {w.x, w.y, w.z, w.w};
  unsigned short h[4], lo[4];
#pragma unroll
  for (int j = 0; j < 4; ++j) {
    h[j] = bf16_rne(f[j]);
    float r = f[j] - __uint_as_float((unsigned)h[j] << 16);
    lo[j] = bf16_rne(r);
  }
  *(uint2*)(Whi + i) = make_uint2(h[0] | ((unsigned)h[1] << 16), h[2] | ((unsigned)h[3] << 16));
  *(uint2*)(Wlo + i) = make_uint2(lo[0] | ((unsigned)lo[1] << 16), lo[2] | ((unsigned)lo[3] << 16));
}

// ---------------- proj = x @ W^T via MFMA bf16x3 (R5-proven) -----------------
#define MM3(ACC, AH, AL, BH, BL)                                        \
  ACC = __builtin_amdgcn_mfma_f32_16x16x32_bf16(AL, BH, ACC, 0, 0, 0);  \
  ACC = __builtin_amdgcn_mfma_f32_16x16x32_bf16(AH, BL, ACC, 0, 0, 0);  \
  ACC = __builtin_amdgcn_mfma_f32_16x16x32_bf16(AH, BH, ACC, 0, 0, 0);

#define LOADB(P, S)                                   \
  {                                                   \
    const int kb = ((S) & 15) * 32;                   \
    P##h0 = *(const short8*)(bh + kb);                \
    P##h1 = *(const short8*)(bh + 8192 + kb);         \
    P##h2 = *(const short8*)(bh + 16384 + kb);        \
    P##h3 = *(const short8*)(bh + 24576 + kb);        \
    P##l0 = *(const short8*)(bl + kb);                \
    P##l1 = *(const short8*)(bl + 8192 + kb);         \
    P##l2 = *(const short8*)(bl + 16384 + kb);        \
    P##l3 = *(const short8*)(bl + 24576 + kb);        \
  }

#define LOADA(Aa, Ab, S)                              \
  {                                                   \
    const int ka = ((S) & 15) * 32;                   \
    Aa = *(const float4*)(xr + ka);                   \
    Ab = *(const float4*)(xr + ka + 4);               \
  }

#define SUBSTEP(Aa, Ab, P, SA, SB)                    \
  {                                                   \
    short8 ahi, alo;                                  \
    cvt8(Aa, Ab, ahi, alo);                           \
    MM3(acc0, ahi, alo, P##h0, P##l0);                \
    MM3(acc1, ahi, alo, P##h1, P##l1);                \
    MM3(acc2, ahi, alo, P##h2, P##l2);                \
    MM3(acc3, ahi, alo, P##h3, P##l3);                \
    LOADB(P, SB);                                     \
    LOADA(Aa, Ab, SA);                                \
  }

__global__ __launch_bounds__(64) void k_proj(const float* __restrict__ x,
                                             const short* __restrict__ Whi,
                                             const short* __restrict__ Wlo,
                                             float* __restrict__ proj) {
  const int row0 = blockIdx.x * 16;
  const int l = threadIdx.x;
  const int m = l & 15;
  const int ko = (l >> 4) * 8;
  const float* xr = x + (size_t)(row0 + m) * D_IN + ko;
  const short* bh = Whi + (size_t)m * D_IN + ko;
  const short* bl = Wlo + (size_t)m * D_IN + ko;

  f32x4 acc0 = {0.f, 0.f, 0.f, 0.f}, acc1 = acc0, acc2 = acc0, acc3 = acc0;
  float4 A0a, A0b, A1a, A1b, A2a, A2b, A3a, A3b;
  short8 Xh0, Xh1, Xh2, Xh3, Xl0, Xl1, Xl2, Xl3;
  short8 Yh0, Yh1, Yh2, Yh3, Yl0, Yl1, Yl2, Yl3;
  LOADA(A0a, A0b, 0); LOADA(A1a, A1b, 1); LOADA(A2a, A2b, 2); LOADA(A3a, A3b, 3);
  LOADB(X, 0); LOADB(Y, 1);

#pragma unroll
  for (int it = 0; it < 4; ++it) {
    const int s = it * 4;
    SUBSTEP(A0a, A0b, X, s + 4, s + 2);
    SUBSTEP(A1a, A1b, Y, s + 5, s + 3);
    SUBSTEP(A2a, A2b, X, s + 6, s + 4);
    SUBSTEP(A3a, A3b, Y, s + 7, s + 5);
  }

  const int r0 = (l >> 4) * 4;
#pragma unroll
  for (int r = 0; r < 4; ++r) {
    float* pr = proj + (size_t)(row0 + r0 + r) * PDIM + m;
    pr[0] = acc0[r]; pr[16] = acc1[r]; pr[32] = acc2[r]; pr[48] = acc3[r];
  }
}

// ---------------- pass 1: LDS-free, dt inline, zero-init scan ----------------
// proj rows are wave-uniform (depend on t only) -> scalar loads, SGPR-resident.
#define S1_LOOP                                                              \
  _Pragma("unroll")                                                          \
  for (int j = 0; j < LCH; ++j) {                                            \
    const float4* pj = (const float4*)(pb + j * PDIM);                       \
    float4 pp[8];                                                            \
    _Pragma("unroll")                                                        \
    for (int k = 0; k < 8; ++k) pp[k] = pj[k];                               \
    float c0 = bb, c1 = 0.f, c2 = 0.f, c3 = 0.f;                             \
    _Pragma("unroll")                                                        \
    for (int k = 0; k < 8; ++k) {                                            \
      c0 = fmaf(pp[k].x, w4[k].x, c0);                                       \
      c1 = fmaf(pp[k].y, w4[k].y, c1);                                       \
      c2 = fmaf(pp[k].z, w4[k].z, c2);                                       \
      c3 = fmaf(pp[k].w, w4[k].w, c3);                                       \
    }                                                                        \
    const float acc = (c0 + c1) + (c2 + c3);                                 \
    const float ee = fast_exp2(acc * LOG2E);                                 \
    const float dtc = (acc > 20.f) ? acc : LN2 * fast_log2(1.f + ee);        \
    dp[(size_t)j * D_IN] = (f16)dtc;                                         \
    sd += dtc;                                                               \
    bpow *= beta;                                                            \
    const float u = alpha * dtc * xs[j];                                     \
    float4 bq[4];                                                            \
    _Pragma("unroll")                                                        \
    for (int k = 0; k < 4; ++k) bq[k] = pj[8 + k];                           \
    const float* Bf = (const float*)bq;                                      \
    AR_INIT;                                                                 \
    _Pragma("unroll")                                                        \
    for (int n = 0; n < 16; ++n) {                                           \
      AR_STEP;                                                               \
      v[n] = fmaf(beta, v[n], u * Bf[n]);                                    \
      h[n] = fmaf(ar, h[n], v[n]);                                           \
      cv[n] = fmaf(ar, cv[n], bpow);                                         \
    }                                                                        \
  }

__global__ __launch_bounds__(256) void k_scan1(const float* __restrict__ x,
                                               const float* __restrict__ proj,
                                               const float* __restrict__ A_log,
                                               const float* __restrict__ W_dt,
                                               const float* __restrict__ b_dt,
                                               const float* __restrict__ alpha_p,
                                               const float* __restrict__ beta_p,
                                               f16* __restrict__ hh,
                                               f16* __restrict__ vh,
                                               f16* __restrict__ cvv,
                                               float* __restrict__ sdt,
                                               f16* __restrict__ dth) {
  const int c = blockIdx.x, b = blockIdx.z;
  const int d = blockIdx.y * 256 + threadIdx.x;
  const int t0 = c * LCH;
  const float* pb = proj + ((size_t)b * LSEQ + t0) * PDIM;  // uniform addr

  float xs[LCH];
  {
    const float* xp = x + ((size_t)b * LSEQ + t0) * D_IN + d;
#pragma unroll
    for (int j = 0; j < LCH; ++j) xs[j] = xp[(size_t)j * D_IN];
  }
  float4 w4[8];
  {
    const float4* wp = (const float4*)(W_dt + (size_t)d * DTR);
#pragma unroll
    for (int i = 0; i < 8; ++i) w4[i] = wp[i];
  }
  const float bb = b_dt[d];
  const float alpha = alpha_p[0];
  const float beta = 1.f / (1.f + __expf(-beta_p[0]));
  float a0;
  const bool pw = detectA2(A_log, d, a0);

  f16* dp = dth + ((size_t)b * LSEQ + t0) * D_IN + d;
  float h[16] = {}, v[16] = {}, cv[16] = {};
  float bpow = 1.f, sd = 0.f;

  if (pw) {
#define AR_INIT const float r = fast_exp2(dtc * a0); float ar = 1.f
#define AR_STEP ar *= r
    S1_LOOP
#undef AR_INIT
#undef AR_STEP
  } else {
    // never-taken fallback (pw holds for arange A); volatile reloads keep
    // register pressure out of the hot path.
    volatile const float* av = A_log + (size_t)d * D_ST;
#define AR_INIT float ar
#define AR_STEP ar = fast_exp2(dtc * (-__expf(av[n]) * LOG2E))
    S1_LOOP
#undef AR_INIT
#undef AR_STEP
  }

  const size_t base = ((size_t)(b * NCH + c) * D_IN + d) * D_ST;
  st16h(hh + base, h);
  st16h(vh + base, v);
  st16h(cvv + base, cv);
  sdt[(size_t)(b * NCH + c) * D_IN + d] = sd;
}

// ---------------- fixup: scan over 256 chunks; group-8 lookahead -------------
__global__ __launch_bounds__(64) void k_fix(f16* __restrict__ hh,
                                            f16* __restrict__ vh,
                                            const f16* __restrict__ cvv,
                                            const float* __restrict__ sdt,
                                            const float* __restrict__ A_log,
                                            const float* __restrict__ beta_p) {
  const int g = blockIdx.x * 64 + threadIdx.x;  // 16384 = B * D * N
  const int b = g >> 13;
  const int dn = g & 8191;
  const float beta = 1.f / (1.f + __expf(-beta_p[0]));
  const float A2 = -__expf(A_log[dn]) * LOG2E;
  float bL = beta;
#pragma unroll
  for (int i = 0; i < 4; ++i) bL *= bL;  // beta^16 = beta^LCH

  const size_t cs = (size_t)D_IN * D_ST;
  const size_t base = (size_t)b * NCH * cs + dn;
  const size_t sbase = (size_t)b * NCH * D_IN + (dn >> 4);

  float hg[8], vg[8], cg[8], sg[8];
#pragma unroll
  for (int i = 0; i < 8; ++i) {
    hg[i] = (float)hh[base + i * cs];
    vg[i] = (float)vh[base + i * cs];
    cg[i] = (float)cvv[base + i * cs];
    sg[i] = sdt[sbase + i * D_IN];
  }
  float H = 0.f, V = 0.f;
  for (int c0 = 0; c0 < NCH; c0 += 8) {
    const int cp = (c0 + 8) & (NCH - 1);  // wraps; last prefetch unused
    float hn[8], vn[8], cn[8], sn[8];
#pragma unroll
    for (int i = 0; i < 8; ++i) {
      hn[i] = (float)hh[base + (size_t)(cp + i) * cs];
      vn[i] = (float)vh[base + (size_t)(cp + i) * cs];
      cn[i] = (float)cvv[base + (size_t)(cp + i) * cs];
      sn[i] = sdt[sbase + (size_t)(cp + i) * D_IN];
    }
#pragma unroll
    for (int i = 0; i < 8; ++i) {
      hh[base + (size_t)(c0 + i) * cs] = (f16)H;
      vh[base + (size_t)(c0 + i) * cs] = (f16)V;
      const float Pa = fast_exp2(sg[i] * A2);
      const float Hn = fmaf(Pa, H, fmaf(cg[i], V, hg[i]));
      V = fmaf(bL, V, vg[i]);
      H = Hn;
    }
#pragma unroll
    for (int i = 0; i < 8; ++i) { hg[i] = hn[i]; vg[i] = vn[i]; cg[i] = cn[i]; sg[i] = sn[i]; }
  }
}

// ---------------- pass 2: LDS-free, read dt(fp16)+x, emit y ------------------
#define S2_LOOP                                                              \
  _Pragma("unroll")                                                          \
  for (int j = 0; j < LCH; ++j) {                                            \
    const float4* pj = (const float4*)(pb + j * PDIM);                       \
    float4 bq[8];                                                            \
    _Pragma("unroll")                                                        \
    for (int k = 0; k < 8; ++k) bq[k] = pj[8 + k];                           \
    const float* Bf = (const float*)bq;                                      \
    const float dtc = dtv[j], xv = xs[j];                                    \
    const float u = alpha * dtc * xv;                                        \
    float y0 = 0.f, y1 = 0.f, y2 = 0.f, y3 = 0.f;                            \
    AR_INIT;                                                                 \
    _Pragma("unroll")                                                        \
    for (int n = 0; n < 16; ++n) {                                           \
      AR_STEP;                                                               \
      v[n] = fmaf(beta, v[n], u * Bf[n]);                                    \
      h[n] = fmaf(ar, h[n], v[n]);                                           \
      float hc = h[n] * Bf[16 + n];                                          \
      if ((n & 3) == 0) y0 += hc;                                            \
      else if ((n & 3) == 1) y1 += hc;                                       \
      else if ((n & 3) == 2) y2 += hc;                                       \
      else y3 += hc;                                                         \
    }                                                                        \
    op[(size_t)j * D_IN] = (y0 + y1) + (y2 + y3) + Dv * xv;                  \
  }

__global__ __launch_bounds__(256) void k_scan2(const float* __restrict__ x,
                                               const f16* __restrict__ dth,
                                               const float* __restrict__ proj,
                                               const float* __restrict__ A_log,
                                               const float* __restrict__ D_param,
                                               const float* __restrict__ alpha_p,
                                               const float* __restrict__ beta_p,
                                               const f16* __restrict__ hh,
                                               const f16* __restrict__ vh,
                                               float* __restrict__ out) {
  const int c = blockIdx.x, b = blockIdx.z;
  const int d = blockIdx.y * 256 + threadIdx.x;
  const int t0 = c * LCH;
  const float* pb = proj + ((size_t)b * LSEQ + t0) * PDIM;  // uniform addr

  float xs[LCH], dtv[LCH];
  {
    const float* xp = x + ((size_t)b * LSEQ + t0) * D_IN + d;
    const f16* dp = dth + ((size_t)b * LSEQ + t0) * D_IN + d;
#pragma unroll
    for (int j = 0; j < LCH; ++j) xs[j] = xp[(size_t)j * D_IN];
#pragma unroll
    for (int j = 0; j < LCH; ++j) dtv[j] = (float)dp[(size_t)j * D_IN];
  }
  const float alpha = alpha_p[0];
  const float beta = 1.f / (1.f + __expf(-beta_p[0]));
  const float Dv = D_param[d];
  float a0;
  const bool pw = detectA2(A_log, d, a0);
  const size_t ibase = ((size_t)(b * NCH + c) * D_IN + d) * D_ST;
  float h[16], v[16];
  ld16h(hh + ibase, h);
  ld16h(vh + ibase, v);

  float* op = out + ((size_t)b * LSEQ + t0) * D_IN + d;
  if (pw) {
#define AR_INIT const float r = fast_exp2(dtc * a0); float ar = 1.f
#define AR_STEP ar *= r
    S2_LOOP
#undef AR_INIT
#undef AR_STEP
  } else {
    volatile const float* av = A_log + (size_t)d * D_ST;
#define AR_INIT float ar
#define AR_STEP ar = fast_exp2(dtc * (-__expf(av[n]) * LOG2E))
    S2_LOOP
#undef AR_INIT
#undef AR_STEP
  }
}

extern "C" void kernel_launch(void* const* d_in, const int* in_sizes, int n_in,
                              void* d_out, int out_size, void* d_ws, size_t ws_size,
                              hipStream_t stream) {
  const float* x = (const float*)d_in[0];
  const float* A_log = (const float*)d_in[1];
  const float* D_param = (const float*)d_in[2];
  const float* W_xproj = (const float*)d_in[3];
  const float* W_dt = (const float*)d_in[4];
  const float* b_dt = (const float*)d_in[5];
  const float* alpha = (const float*)d_in[6];
  const float* beta_logit = (const float*)d_in[7];
  float* out = (float*)d_out;

  const size_t NST = (size_t)BSZ * NCH * D_IN * D_ST;  // 4194304
  float* ws = (float*)d_ws;
  float* proj = ws;                                  // 524288 floats
  float* sdt = proj + (size_t)BSZ * LSEQ * PDIM;     // 262144 floats
  f16* hh = (f16*)(sdt + (size_t)BSZ * NCH * D_IN);  // 4194304 halves
  f16* vh = hh + NST;
  f16* cvv = vh + NST;
  f16* dth = cvv + NST;                              // B*L*D halves
  short* Whi = (short*)(dth + (size_t)BSZ * LSEQ * D_IN);
  short* Wlo = Whi + (size_t)PDIM * D_IN;            // total ~37 MB

  k_wprep<<<dim3(PDIM * D_IN / 1024), dim3(256), 0, stream>>>(W_xproj, Whi, Wlo);
  k_proj<<<dim3(BSZ * LSEQ / 16), dim3(64), 0, stream>>>(x, Whi, Wlo, proj);
  k_scan1<<<dim3(NCH, D_IN / 256, BSZ), dim3(256), 0, stream>>>(
      x, proj, A_log, W_dt, b_dt, alpha, beta_logit, hh, vh, cvv, sdt, dth);
  k_fix<<<dim3(BSZ * D_IN * D_ST / 64), dim3(64), 0, stream>>>(hh, vh, cvv, sdt, A_log,
                                                               beta_logit);
  k_scan2<<<dim3(NCH, D_IN / 256, BSZ), dim3(256), 0, stream>>>(
      x, dth, proj, A_log, D_param, alpha, beta_logit, hh, vh, out);
}

// Round 5
// 167.841 us; speedup vs baseline: 1.2471x; 1.0479x over previous
//
#include <hip/hip_runtime.h>

// MomentumSSM B=2, L=4096, D=512, N=16, R=32, P=64 — chunk-parallel scan, NCH=256.
// R19: R18 scans (LDS-free) + k_proj K-split x4 occupancy fix + k_fix group-16.
//   k_wprep -> k_proj (MFMA bf16x3, 4-wave K-split) -> k_scan1 -> k_fix -> k_scan2
// - k_proj was 512x64 = 0.5 waves/SIMD (zero latency hiding, ~40us est). Now 256-thr
//   blocks: wave wq owns K-slice [wq*128,(wq+1)*128); partial accs reduced via LDS;
//   coalesced float4 C-stores. Same MFMA count, same x traffic, 4x waves.
// - k_fix: group-8 -> group-16 lookahead (32 -> 16 latency-gated iterations).
// - scans: R18 LDS-free bodies (proj rows are wave-uniform -> scalar/global reads).
// TOOLCHAIN LANDMINES (measured R15/R16):
//   * __launch_bounds__(256, 4) caps VGPR at 64 -> scratch spills. Never use arg 2.
//   * runtime-indexed private arrays -> promote-alloca-to-LDS + bank conflicts.
//   * materializing dt through HBM between kernels (R15 k_dt): +37us net loss.
// Disproven: coop launch, manual grid barrier (~80us/sync), dt recompute in scan2,
// scan1 lane-pair split (R17 neutral), scan LDS elimination (R18 neutral — scans are
// NOT operand-path- or wave-count-bound; leave them).
//
// v_t = beta*v + alpha*inp ; h_t = a_t*h + v ; a_t = exp(dt*A_n)
// chunk map: h_end = Pa*H0 + cv*V0 + hhat ; v_end = beta^LCH*V0 + vhat

#define D_IN 512
#define D_ST 16
#define DTR  32
#define BSZ  2
#define LSEQ 4096
#define PDIM 64
#define NCH  256
#define LCH  (LSEQ / NCH)  // 16
#define LOG2E 1.44269504f
#define LN2   0.69314718f

typedef __attribute__((ext_vector_type(8))) short short8;
typedef __attribute__((ext_vector_type(4))) float f32x4;
typedef _Float16 f16;
typedef __attribute__((ext_vector_type(8))) _Float16 f16x8;

__device__ inline float fast_exp2(float x) { return __builtin_amdgcn_exp2f(x); }
__device__ inline float fast_log2(float x) { return __builtin_amdgcn_logf(x); }

__device__ inline unsigned short bf16_rne(float f) {
  unsigned b = __float_as_uint(f);
  return (unsigned short)((b + 0x7fffu + ((b >> 16) & 1u)) >> 16);
}

__device__ inline void cvt8(const float4 u, const float4 v, short8& hi, short8& lo) {
  float f[8] = {u.x, u.y, u.z, u.w, v.x, v.y, v.z, v.w};
#pragma unroll
  for (int i = 0; i < 8; ++i) {
    unsigned short h = bf16_rne(f[i]);
    hi[i] = (short)h;
    float r = f[i] - __uint_as_float((unsigned)h << 16);
    lo[i] = (short)bf16_rne(r);
  }
}

__device__ inline void st16h(f16* p, const float* s) {
  f16 t[16];
#pragma unroll
  for (int i = 0; i < 16; ++i) t[i] = (f16)s[i];
  *(f16x8*)p = *(f16x8*)&t[0];
  *(f16x8*)(p + 8) = *(f16x8*)&t[8];
}
__device__ inline void ld16h(const f16* p, float* d) {
  f16x8 a = *(const f16x8*)p;
  f16x8 b = *(const f16x8*)(p + 8);
#pragma unroll
  for (int i = 0; i < 8; ++i) { d[i] = (float)a[i]; d[8 + i] = (float)b[i]; }
}

// pw check: A2[n] = -exp(A_log[d][n])*LOG2E is an arithmetic progression
#define PWCHK(val, n)                                                        \
  pw = pw && (fabsf((val) - (float)((n) + 1) * a0) <=                        \
              2e-5f * fabsf((float)((n) + 1) * a0));

__device__ inline bool detectA2(const float* __restrict__ A_log, int d, float& a0) {
  const float4* ap = (const float4*)(A_log + (size_t)d * D_ST);
  float4 r0 = ap[0], r1 = ap[1], r2 = ap[2], r3 = ap[3];
  float4 e0 = make_float4(-__expf(r0.x) * LOG2E, -__expf(r0.y) * LOG2E,
                          -__expf(r0.z) * LOG2E, -__expf(r0.w) * LOG2E);
  float4 e1 = make_float4(-__expf(r1.x) * LOG2E, -__expf(r1.y) * LOG2E,
                          -__expf(r1.z) * LOG2E, -__expf(r1.w) * LOG2E);
  float4 e2 = make_float4(-__expf(r2.x) * LOG2E, -__expf(r2.y) * LOG2E,
                          -__expf(r2.z) * LOG2E, -__expf(r2.w) * LOG2E);
  float4 e3 = make_float4(-__expf(r3.x) * LOG2E, -__expf(r3.y) * LOG2E,
                          -__expf(r3.z) * LOG2E, -__expf(r3.w) * LOG2E);
  a0 = e0.x;
  bool pw = true;
  PWCHK(e0.y, 1) PWCHK(e0.z, 2) PWCHK(e0.w, 3)
  PWCHK(e1.x, 4) PWCHK(e1.y, 5) PWCHK(e1.z, 6) PWCHK(e1.w, 7)
  PWCHK(e2.x, 8) PWCHK(e2.y, 9) PWCHK(e2.z, 10) PWCHK(e2.w, 11)
  PWCHK(e3.x, 12) PWCHK(e3.y, 13) PWCHK(e3.z, 14) PWCHK(e3.w, 15)
  return pw;
}

// ---------------- W -> bf16 hi/lo split --------------------------------------
__global__ __launch_bounds__(256) void k_wprep(const float* __restrict__ W,
                                               short* __restrict__ Whi,
                                               short* __restrict__ Wlo) {
  const int i = (blockIdx.x * 256 + threadIdx.x) * 4;
  float4 w = *(const float4*)(W + i);
  float f[4] = {w.x, w.y, w.z, w.w};
  unsigned short h[4], lo[4];
#pragma unroll
  for (int j = 0; j < 4; ++j) {
    h[j] = bf16_rne(f[j]);
    float r = f[j] - __uint_as_float((unsigned)h[j] << 16);
    lo[j] = bf16_rne(r);
  }
  *(uint2*)(Whi + i) = make_uint2(h[0] | ((unsigned)h[1] << 16), h[2] | ((unsigned)h[3] << 16));
  *(uint2*)(Wlo + i) = make_uint2(lo[0] | ((unsigned)lo[1] << 16), lo[2] | ((unsigned)lo[3] << 16));
}

// ---------------- proj = x @ W^T via MFMA bf16x3, 4-wave K-split -------------
#define MM3(ACC, AH, AL, BH, BL)                                        \
  ACC = __builtin_amdgcn_mfma_f32_16x16x32_bf16(AL, BH, ACC, 0, 0, 0);  \
  ACC = __builtin_amdgcn_mfma_f32_16x16x32_bf16(AH, BL, ACC, 0, 0, 0);  \
  ACC = __builtin_amdgcn_mfma_f32_16x16x32_bf16(AH, BH, ACC, 0, 0, 0);

#define LOADB(P, S)                                   \
  {                                                   \
    const int kb = (S) * 32;                          \
    P##h0 = *(const short8*)(bh + kb);                \
    P##h1 = *(const short8*)(bh + 8192 + kb);         \
    P##h2 = *(const short8*)(bh + 16384 + kb);        \
    P##h3 = *(const short8*)(bh + 24576 + kb);        \
    P##l0 = *(const short8*)(bl + kb);                \
    P##l1 = *(const short8*)(bl + 8192 + kb);         \
    P##l2 = *(const short8*)(bl + 16384 + kb);        \
    P##l3 = *(const short8*)(bl + 24576 + kb);        \
  }

#define LOADA(Aa, Ab, S)                              \
  {                                                   \
    const int ka = (S) * 32;                          \
    Aa = *(const float4*)(xr + ka);                   \
    Ab = *(const float4*)(xr + ka + 4);               \
  }

#define COMPSTEP(Aa, Ab, P)                           \
  {                                                   \
    short8 ahi, alo;                                  \
    cvt8(Aa, Ab, ahi, alo);                           \
    MM3(acc0, ahi, alo, P##h0, P##l0);                \
    MM3(acc1, ahi, alo, P##h1, P##l1);                \
    MM3(acc2, ahi, alo, P##h2, P##l2);                \
    MM3(acc3, ahi, alo, P##h3, P##l3);                \
  }

__global__ __launch_bounds__(256) void k_proj(const float* __restrict__ x,
                                              const short* __restrict__ Whi,
                                              const short* __restrict__ Wlo,
                                              float* __restrict__ proj) {
  __shared__ float Pacc[4][16][64];  // 16 KB: per-wave partial C tiles
  const int row0 = blockIdx.x * 16;
  const int l = threadIdx.x & 63;
  const int wq = threadIdx.x >> 6;             // K-quarter owner
  const int m = l & 15;
  const int ko = (l >> 4) * 8 + wq * 128;      // this wave's K window
  const float* xr = x + (size_t)(row0 + m) * D_IN + ko;
  const short* bh = Whi + (size_t)m * D_IN + ko;
  const short* bl = Wlo + (size_t)m * D_IN + ko;

  f32x4 acc0 = {0.f, 0.f, 0.f, 0.f}, acc1 = acc0, acc2 = acc0, acc3 = acc0;
  float4 A0a, A0b, A1a, A1b, A2a, A2b, A3a, A3b;
  short8 Xh0, Xh1, Xh2, Xh3, Xl0, Xl1, Xl2, Xl3;
  short8 Yh0, Yh1, Yh2, Yh3, Yl0, Yl1, Yl2, Yl3;
  LOADA(A0a, A0b, 0); LOADA(A1a, A1b, 1); LOADA(A2a, A2b, 2); LOADA(A3a, A3b, 3);
  LOADB(X, 0); LOADB(Y, 1);

  COMPSTEP(A0a, A0b, X); LOADB(X, 2);
  COMPSTEP(A1a, A1b, Y); LOADB(Y, 3);
  COMPSTEP(A2a, A2b, X);
  COMPSTEP(A3a, A3b, Y);

  const int r0 = (l >> 4) * 4;
#pragma unroll
  for (int r = 0; r < 4; ++r) {
    Pacc[wq][r0 + r][m] = acc0[r];
    Pacc[wq][r0 + r][16 + m] = acc1[r];
    Pacc[wq][r0 + r][32 + m] = acc2[r];
    Pacc[wq][r0 + r][48 + m] = acc3[r];
  }
  __syncthreads();

  const int orow = threadIdx.x >> 4;           // 0..15
  const int ocol = (threadIdx.x & 15) * 4;     // 0..60
  float4 s0 = *(const float4*)&Pacc[0][orow][ocol];
  float4 s1 = *(const float4*)&Pacc[1][orow][ocol];
  float4 s2 = *(const float4*)&Pacc[2][orow][ocol];
  float4 s3 = *(const float4*)&Pacc[3][orow][ocol];
  float4 o = make_float4((s0.x + s1.x) + (s2.x + s3.x), (s0.y + s1.y) + (s2.y + s3.y),
                         (s0.z + s1.z) + (s2.z + s3.z), (s0.w + s1.w) + (s2.w + s3.w));
  *(float4*)(proj + (size_t)(row0 + orow) * PDIM + ocol) = o;
}

// ---------------- pass 1: LDS-free, dt inline, zero-init scan ----------------
#define S1_LOOP                                                              \
  _Pragma("unroll")                                                          \
  for (int j = 0; j < LCH; ++j) {                                            \
    const float4* pj = (const float4*)(pb + j * PDIM);                       \
    float4 pp[8];                                                            \
    _Pragma("unroll")                                                        \
    for (int k = 0; k < 8; ++k) pp[k] = pj[k];                               \
    float c0 = bb, c1 = 0.f, c2 = 0.f, c3 = 0.f;                             \
    _Pragma("unroll")                                                        \
    for (int k = 0; k < 8; ++k) {                                            \
      c0 = fmaf(pp[k].x, w4[k].x, c0);                                       \
      c1 = fmaf(pp[k].y, w4[k].y, c1);                                       \
      c2 = fmaf(pp[k].z, w4[k].z, c2);                                       \
      c3 = fmaf(pp[k].w, w4[k].w, c3);                                       \
    }                                                                        \
    const float acc = (c0 + c1) + (c2 + c3);                                 \
    const float ee = fast_exp2(acc * LOG2E);                                 \
    const float dtc = (acc > 20.f) ? acc : LN2 * fast_log2(1.f + ee);        \
    dp[(size_t)j * D_IN] = (f16)dtc;                                         \
    sd += dtc;                                                               \
    bpow *= beta;                                                            \
    const float u = alpha * dtc * xs[j];                                     \
    float4 bq[4];                                                            \
    _Pragma("unroll")                                                        \
    for (int k = 0; k < 4; ++k) bq[k] = pj[8 + k];                           \
    const float* Bf = (const float*)bq;                                      \
    AR_INIT;                                                                 \
    _Pragma("unroll")                                                        \
    for (int n = 0; n < 16; ++n) {                                           \
      AR_STEP;                                                               \
      v[n] = fmaf(beta, v[n], u * Bf[n]);                                    \
      h[n] = fmaf(ar, h[n], v[n]);                                           \
      cv[n] = fmaf(ar, cv[n], bpow);                                         \
    }                                                                        \
  }

__global__ __launch_bounds__(256) void k_scan1(const float* __restrict__ x,
                                               const float* __restrict__ proj,
                                               const float* __restrict__ A_log,
                                               const float* __restrict__ W_dt,
                                               const float* __restrict__ b_dt,
                                               const float* __restrict__ alpha_p,
                                               const float* __restrict__ beta_p,
                                               f16* __restrict__ hh,
                                               f16* __restrict__ vh,
                                               f16* __restrict__ cvv,
                                               float* __restrict__ sdt,
                                               f16* __restrict__ dth) {
  const int c = blockIdx.x, b = blockIdx.z;
  const int d = blockIdx.y * 256 + threadIdx.x;
  const int t0 = c * LCH;
  const float* pb = proj + ((size_t)b * LSEQ + t0) * PDIM;  // uniform addr

  float xs[LCH];
  {
    const float* xp = x + ((size_t)b * LSEQ + t0) * D_IN + d;
#pragma unroll
    for (int j = 0; j < LCH; ++j) xs[j] = xp[(size_t)j * D_IN];
  }
  float4 w4[8];
  {
    const float4* wp = (const float4*)(W_dt + (size_t)d * DTR);
#pragma unroll
    for (int i = 0; i < 8; ++i) w4[i] = wp[i];
  }
  const float bb = b_dt[d];
  const float alpha = alpha_p[0];
  const float beta = 1.f / (1.f + __expf(-beta_p[0]));
  float a0;
  const bool pw = detectA2(A_log, d, a0);

  f16* dp = dth + ((size_t)b * LSEQ + t0) * D_IN + d;
  float h[16] = {}, v[16] = {}, cv[16] = {};
  float bpow = 1.f, sd = 0.f;

  if (pw) {
#define AR_INIT const float r = fast_exp2(dtc * a0); float ar = 1.f
#define AR_STEP ar *= r
    S1_LOOP
#undef AR_INIT
#undef AR_STEP
  } else {
    volatile const float* av = A_log + (size_t)d * D_ST;
#define AR_INIT float ar
#define AR_STEP ar = fast_exp2(dtc * (-__expf(av[n]) * LOG2E))
    S1_LOOP
#undef AR_INIT
#undef AR_STEP
  }

  const size_t base = ((size_t)(b * NCH + c) * D_IN + d) * D_ST;
  st16h(hh + base, h);
  st16h(vh + base, v);
  st16h(cvv + base, cv);
  sdt[(size_t)(b * NCH + c) * D_IN + d] = sd;
}

// ---------------- fixup: scan over 256 chunks; group-16 lookahead ------------
__global__ __launch_bounds__(64) void k_fix(f16* __restrict__ hh,
                                            f16* __restrict__ vh,
                                            const f16* __restrict__ cvv,
                                            const float* __restrict__ sdt,
                                            const float* __restrict__ A_log,
                                            const float* __restrict__ beta_p) {
  const int g = blockIdx.x * 64 + threadIdx.x;  // 16384 = B * D * N
  const int b = g >> 13;
  const int dn = g & 8191;
  const float beta = 1.f / (1.f + __expf(-beta_p[0]));
  const float A2 = -__expf(A_log[dn]) * LOG2E;
  float bL = beta;
#pragma unroll
  for (int i = 0; i < 4; ++i) bL *= bL;  // beta^16 = beta^LCH

  const size_t cs = (size_t)D_IN * D_ST;
  const size_t base = (size_t)b * NCH * cs + dn;
  const size_t sbase = (size_t)b * NCH * D_IN + (dn >> 4);

  float hg[16], vg[16], cg[16], sg[16];
#pragma unroll
  for (int i = 0; i < 16; ++i) {
    hg[i] = (float)hh[base + i * cs];
    vg[i] = (float)vh[base + i * cs];
    cg[i] = (float)cvv[base + i * cs];
    sg[i] = sdt[sbase + i * D_IN];
  }
  float H = 0.f, V = 0.f;
  for (int c0 = 0; c0 < NCH; c0 += 16) {
    const int cp = (c0 + 16) & (NCH - 1);  // wraps; last prefetch unused
    float hn[16], vn[16], cn[16], sn[16];
#pragma unroll
    for (int i = 0; i < 16; ++i) {
      hn[i] = (float)hh[base + (size_t)(cp + i) * cs];
      vn[i] = (float)vh[base + (size_t)(cp + i) * cs];
      cn[i] = (float)cvv[base + (size_t)(cp + i) * cs];
      sn[i] = sdt[sbase + (size_t)(cp + i) * D_IN];
    }
#pragma unroll
    for (int i = 0; i < 16; ++i) {
      hh[base + (size_t)(c0 + i) * cs] = (f16)H;
      vh[base + (size_t)(c0 + i) * cs] = (f16)V;
      const float Pa = fast_exp2(sg[i] * A2);
      const float Hn = fmaf(Pa, H, fmaf(cg[i], V, hg[i]));
      V = fmaf(bL, V, vg[i]);
      H = Hn;
    }
#pragma unroll
    for (int i = 0; i < 16; ++i) { hg[i] = hn[i]; vg[i] = vn[i]; cg[i] = cn[i]; sg[i] = sn[i]; }
  }
}

// ---------------- pass 2: LDS-free, read dt(fp16)+x, emit y ------------------
#define S2_LOOP                                                              \
  _Pragma("unroll")                                                          \
  for (int j = 0; j < LCH; ++j) {                                            \
    const float4* pj = (const float4*)(pb + j * PDIM);                       \
    float4 bq[8];                                                            \
    _Pragma("unroll")                                                        \
    for (int k = 0; k < 8; ++k) bq[k] = pj[8 + k];                           \
    const float* Bf = (const float*)bq;                                      \
    const float dtc = dtv[j], xv = xs[j];                                    \
    const float u = alpha * dtc * xv;                                        \
    float y0 = 0.f, y1 = 0.f, y2 = 0.f, y3 = 0.f;                            \
    AR_INIT;                                                                 \
    _Pragma("unroll")                                                        \
    for (int n = 0; n < 16; ++n) {                                           \
      AR_STEP;                                                               \
      v[n] = fmaf(beta, v[n], u * Bf[n]);                                    \
      h[n] = fmaf(ar, h[n], v[n]);                                           \
      float hc = h[n] * Bf[16 + n];                                          \
      if ((n & 3) == 0) y0 += hc;                                            \
      else if ((n & 3) == 1) y1 += hc;                                       \
      else if ((n & 3) == 2) y2 += hc;                                       \
      else y3 += hc;                                                         \
    }                                                                        \
    op[(size_t)j * D_IN] = (y0 + y1) + (y2 + y3) + Dv * xv;                  \
  }

__global__ __launch_bounds__(256) void k_scan2(const float* __restrict__ x,
                                               const f16* __restrict__ dth,
                                               const float* __restrict__ proj,
                                               const float* __restrict__ A_log,
                                               const float* __restrict__ D_param,
                                               const float* __restrict__ alpha_p,
                                               const float* __restrict__ beta_p,
                                               const f16* __restrict__ hh,
                                               const f16* __restrict__ vh,
                                               float* __restrict__ out) {
  const int c = blockIdx.x, b = blockIdx.z;
  const int d = blockIdx.y * 256 + threadIdx.x;
  const int t0 = c * LCH;
  const float* pb = proj + ((size_t)b * LSEQ + t0) * PDIM;  // uniform addr

  float xs[LCH], dtv[LCH];
  {
    const float* xp = x + ((size_t)b * LSEQ + t0) * D_IN + d;
    const f16* dp = dth + ((size_t)b * LSEQ + t0) * D_IN + d;
#pragma unroll
    for (int j = 0; j < LCH; ++j) xs[j] = xp[(size_t)j * D_IN];
#pragma unroll
    for (int j = 0; j < LCH; ++j) dtv[j] = (float)dp[(size_t)j * D_IN];
  }
  const float alpha = alpha_p[0];
  const float beta = 1.f / (1.f + __expf(-beta_p[0]));
  const float Dv = D_param[d];
  float a0;
  const bool pw = detectA2(A_log, d, a0);
  const size_t ibase = ((size_t)(b * NCH + c) * D_IN + d) * D_ST;
  float h[16], v[16];
  ld16h(hh + ibase, h);
  ld16h(vh + ibase, v);

  float* op = out + ((size_t)b * LSEQ + t0) * D_IN + d;
  if (pw) {
#define AR_INIT const float r = fast_exp2(dtc * a0); float ar = 1.f
#define AR_STEP ar *= r
    S2_LOOP
#undef AR_INIT
#undef AR_STEP
  } else {
    volatile const float* av = A_log + (size_t)d * D_ST;
#define AR_INIT float ar
#define AR_STEP ar = fast_exp2(dtc * (-__expf(av[n]) * LOG2E))
    S2_LOOP
#undef AR_INIT
#undef AR_STEP
  }
}

extern "C" void kernel_launch(void* const* d_in, const int* in_sizes, int n_in,
                              void* d_out, int out_size, void* d_ws, size_t ws_size,
                              hipStream_t stream) {
  const float* x = (const float*)d_in[0];
  const float* A_log = (const float*)d_in[1];
  const float* D_param = (const float*)d_in[2];
  const float* W_xproj = (const float*)d_in[3];
  const float* W_dt = (const float*)d_in[4];
  const float* b_dt = (const float*)d_in[5];
  const float* alpha = (const float*)d_in[6];
  const float* beta_logit = (const float*)d_in[7];
  float* out = (float*)d_out;

  const size_t NST = (size_t)BSZ * NCH * D_IN * D_ST;  // 4194304
  float* ws = (float*)d_ws;
  float* proj = ws;                                  // 524288 floats
  float* sdt = proj + (size_t)BSZ * LSEQ * PDIM;     // 262144 floats
  f16* hh = (f16*)(sdt + (size_t)BSZ * NCH * D_IN);  // 4194304 halves
  f16* vh = hh + NST;
  f16* cvv = vh + NST;
  f16* dth = cvv + NST;                              // B*L*D halves
  short* Whi = (short*)(dth + (size_t)BSZ * LSEQ * D_IN);
  short* Wlo = Whi + (size_t)PDIM * D_IN;            // total ~37 MB

  k_wprep<<<dim3(PDIM * D_IN / 1024), dim3(256), 0, stream>>>(W_xproj, Whi, Wlo);
  k_proj<<<dim3(BSZ * LSEQ / 16), dim3(256), 0, stream>>>(x, Whi, Wlo, proj);
  k_scan1<<<dim3(NCH, D_IN / 256, BSZ), dim3(256), 0, stream>>>(
      x, proj, A_log, W_dt, b_dt, alpha, beta_logit, hh, vh, cvv, sdt, dth);
  k_fix<<<dim3(BSZ * D_IN * D_ST / 64), dim3(64), 0, stream>>>(hh, vh, cvv, sdt, A_log,
                                                               beta_logit);
  k_scan2<<<dim3(NCH, D_IN / 256, BSZ), dim3(256), 0, stream>>>(
      x, dth, proj, A_log, D_param, alpha, beta_logit, hh, vh, out);
}